// Round 1
// baseline (895.312 us; speedup 1.0000x reference)
//
#include <hip/hip_runtime.h>
#include <hip/hip_bf16.h>
#include <math.h>

// ---------------------------------------------------------------------------
// Problem: sum over 2 spin groups of log|mlp2(prod_pairs(mlp1(hi,hj)-mlp1(hj,hi)))|
// Round 0: correct fp32 baseline.
//   - Layer-0 trick: pre-act(i,j) = P[i] + Q[j] + b  with P=h@W1_0[:1024], Q=h@W1_0[1024:]
//   - Generic 64x64x16 fp32 tiled GEMM for L0(PQ)/L1/L2 with fused bias+silu
//   - prod over pairs, mlp2 (k-split + atomics), finalize -> scalar
// ---------------------------------------------------------------------------

#define BM 64
#define BN 64
#define BK 16

__device__ __forceinline__ float silu_f(float x) {
    return x / (1.0f + __expf(-x));
}

// ACT: 0 = bias only, 1 = bias + silu, 2 = raw (no bias, no act)
template<int ACT>
__global__ __launch_bounds__(256)
void gemm_kernel(const float* __restrict__ A, const float* __restrict__ B,
                 const float* __restrict__ bias, float* __restrict__ C,
                 int M, int N, int K) {
    __shared__ float As[BK][BM + 4];
    __shared__ float Bs[BK][BN];
    const int tid = threadIdx.x;
    const int m0 = blockIdx.y * BM;
    const int n0 = blockIdx.x * BN;
    const int tm4 = (tid >> 4) * 4;   // output row offset within tile
    const int tn4 = (tid & 15) * 4;   // output col offset within tile
    // A-tile load mapping: 64 rows x 16 k, one float4 per thread
    const int ar = tid >> 2;          // 0..63
    const int ak = (tid & 3) * 4;     // 0,4,8,12
    // B-tile load mapping: 16 k x 64 n, one float4 per thread
    const int bk = tid >> 4;          // 0..15
    const int bn = (tid & 15) * 4;    // 0..60

    float acc[4][4] = {};
    const int arow = m0 + ar;
    const bool a_ok = (arow < M);
    const float* Aptr = A + (size_t)arow * K + ak;
    const float* Bptr = B + (size_t)bk * N + n0 + bn;

    for (int k0 = 0; k0 < K; k0 += BK) {
        float4 av = a_ok ? *(const float4*)(Aptr + k0)
                         : make_float4(0.f, 0.f, 0.f, 0.f);
        float4 bv = *(const float4*)(Bptr + (size_t)k0 * N);
        As[ak + 0][ar] = av.x;
        As[ak + 1][ar] = av.y;
        As[ak + 2][ar] = av.z;
        As[ak + 3][ar] = av.w;
        *(float4*)&Bs[bk][bn] = bv;
        __syncthreads();
        #pragma unroll
        for (int k = 0; k < BK; ++k) {
            float4 a4 = *(const float4*)&As[k][tm4];
            float4 b4 = *(const float4*)&Bs[k][tn4];
            float aa[4] = {a4.x, a4.y, a4.z, a4.w};
            float bb[4] = {b4.x, b4.y, b4.z, b4.w};
            #pragma unroll
            for (int i2 = 0; i2 < 4; ++i2)
                #pragma unroll
                for (int j2 = 0; j2 < 4; ++j2)
                    acc[i2][j2] = fmaf(aa[i2], bb[j2], acc[i2][j2]);
        }
        __syncthreads();
    }

    float bvals[4] = {0.f, 0.f, 0.f, 0.f};
    if (ACT != 2) {
        float4 b4 = *(const float4*)&bias[n0 + tn4];
        bvals[0] = b4.x; bvals[1] = b4.y; bvals[2] = b4.z; bvals[3] = b4.w;
    }
    #pragma unroll
    for (int i2 = 0; i2 < 4; ++i2) {
        int row = m0 + tm4 + i2;
        if (row < M) {
            float4 ov;
            float* op = (float*)&ov;
            #pragma unroll
            for (int j2 = 0; j2 < 4; ++j2) {
                float v = acc[i2][j2];
                if (ACT != 2) v += bvals[j2];
                if (ACT == 1) v = silu_f(v);
                op[j2] = v;
            }
            *(float4*)&C[(size_t)row * N + n0 + tn4] = ov;
        }
    }
}

// Y1[r][n] = silu(P[a(r)][n] + Q[b(r)][n] + b1_0[n]), r in [0,480)
__global__ __launch_bounds__(256)
void build_y1_kernel(const float* __restrict__ P, const float* __restrict__ Q,
                     const float* __restrict__ b1, float* __restrict__ Y1) {
    const int r = blockIdx.x;
    const int g = r / 240;
    const int rem = r % 240;
    const int o = rem / 120;
    const int p = rem % 120;
    int i = 0, pp = p, cnt = 15;
    while (pp >= cnt) { pp -= cnt; cnt--; i++; }
    const int j = i + 1 + pp;
    const int ai = g * 16 + (o ? j : i);   // first concat half -> P (W rows 0..1023)
    const int bi = g * 16 + (o ? i : j);   // second concat half -> Q
    const float4* Pr = (const float4*)(P + (size_t)ai * 4096);
    const float4* Qr = (const float4*)(Q + (size_t)bi * 4096);
    const float4* Br = (const float4*)b1;
    float4* Yr = (float4*)(Y1 + (size_t)r * 4096);
    for (int c = threadIdx.x; c < 1024; c += 256) {
        float4 pv = Pr[c], qv = Qr[c], bv = Br[c];
        float4 ov;
        ov.x = silu_f(pv.x + qv.x + bv.x);
        ov.y = silu_f(pv.y + qv.y + bv.y);
        ov.z = silu_f(pv.z + qv.z + bv.z);
        ov.w = silu_f(pv.w + qv.w + bv.w);
        Yr[c] = ov;
    }
}

// a[g][c] = prod_p (H[g*240+p][c] - H[g*240+120+p][c])
__global__ __launch_bounds__(256)
void reduce_prod_kernel(const float* __restrict__ H, float* __restrict__ a_buf) {
    const int g = blockIdx.y;
    const int c = blockIdx.x * 256 + threadIdx.x;   // 0..2047
    const float* base = H + (size_t)g * 240 * 2048 + c;
    float prod = 1.0f;
    for (int p = 0; p < 120; ++p) {
        float f = base[(size_t)p * 2048] - base[(size_t)(120 + p) * 2048];
        prod *= f;
    }
    a_buf[g * 2048 + c] = prod;
}

__global__ __launch_bounds__(256)
void init_tpre_kernel(const float* __restrict__ b2_0, float* __restrict__ t_pre) {
    const int idx = blockIdx.x * 256 + threadIdx.x;   // 0..4095
    t_pre[idx] = b2_0[idx & 2047];
}

// t_pre[g][n] += sum_{k in chunk} a[g][k] * W2_0[k][n]
__global__ __launch_bounds__(256)
void mlp2_acc_kernel(const float* __restrict__ a_buf, const float* __restrict__ W,
                     float* __restrict__ t_pre) {
    __shared__ float a_sh[256];
    const int g = blockIdx.z;
    const int kc = blockIdx.y;
    const int nc = blockIdx.x;
    const int tid = threadIdx.x;
    a_sh[tid] = a_buf[g * 2048 + kc * 256 + tid];
    __syncthreads();
    const int n = nc * 256 + tid;
    const float* Wp = W + (size_t)(kc * 256) * 2048 + n;
    float acc = 0.f;
    #pragma unroll 8
    for (int kk = 0; kk < 256; ++kk)
        acc = fmaf(a_sh[kk], Wp[(size_t)kk * 2048], acc);
    atomicAdd(&t_pre[g * 2048 + n], acc);
}

// out = sum_g log|sum_n tanh(t_pre[g][n]) * w2_1[n] + b2_1|
__global__ __launch_bounds__(256)
void finalize_kernel(const float* __restrict__ t_pre, const float* __restrict__ w2_1,
                     const float* __restrict__ b2_1, float* __restrict__ out) {
    __shared__ float red[256];
    const int tid = threadIdx.x;
    float result = 0.0f;
    for (int g = 0; g < 2; ++g) {
        float s = 0.f;
        for (int n = tid; n < 2048; n += 256)
            s += tanhf(t_pre[g * 2048 + n]) * w2_1[n];
        red[tid] = s;
        __syncthreads();
        for (int off = 128; off > 0; off >>= 1) {
            if (tid < off) red[tid] += red[tid + off];
            __syncthreads();
        }
        if (tid == 0) result += logf(fabsf(red[0] + b2_1[0]));
        __syncthreads();
    }
    if (tid == 0) out[0] = result;
}

extern "C" void kernel_launch(void* const* d_in, const int* in_sizes, int n_in,
                              void* d_out, int out_size, void* d_ws, size_t ws_size,
                              hipStream_t stream) {
    const float* h_one = (const float*)d_in[0];   // 32 x 1024
    const float* w1_0  = (const float*)d_in[1];   // 2048 x 4096
    const float* b1_0  = (const float*)d_in[2];   // 4096
    const float* w1_1  = (const float*)d_in[3];   // 4096 x 4096
    const float* b1_1  = (const float*)d_in[4];   // 4096
    const float* w1_2  = (const float*)d_in[5];   // 4096 x 2048
    const float* b1_2  = (const float*)d_in[6];   // 2048
    const float* w2_0  = (const float*)d_in[7];   // 2048 x 2048
    const float* b2_0  = (const float*)d_in[8];   // 2048
    const float* w2_1  = (const float*)d_in[9];   // 2048
    const float* b2_1  = (const float*)d_in[10];  // 1
    float* out = (float*)d_out;

    float* ws    = (float*)d_ws;
    float* P     = ws;                       // 32 x 4096
    float* Q     = P  + (size_t)32 * 4096;   // 32 x 4096
    float* Y1    = Q  + (size_t)32 * 4096;   // 480 x 4096
    float* Y2    = Y1 + (size_t)480 * 4096;  // 480 x 4096
    float* Hb    = Y2 + (size_t)480 * 4096;  // 480 x 2048
    float* a_buf = Hb + (size_t)480 * 2048;  // 2 x 2048
    float* t_pre = a_buf + 2 * 2048;         // 2 x 2048

    // Layer 0 via P/Q trick: P = h @ W1_0[:1024], Q = h @ W1_0[1024:]
    gemm_kernel<2><<<dim3(64, 1), 256, 0, stream>>>(h_one, w1_0, nullptr, P, 32, 4096, 1024);
    gemm_kernel<2><<<dim3(64, 1), 256, 0, stream>>>(h_one, w1_0 + (size_t)1024 * 4096, nullptr, Q, 32, 4096, 1024);
    build_y1_kernel<<<dim3(480), 256, 0, stream>>>(P, Q, b1_0, Y1);

    // Layer 1: Y2 = silu(Y1 @ W1_1 + b1_1)   (480 x 4096, K=4096)
    gemm_kernel<1><<<dim3(64, 8), 256, 0, stream>>>(Y1, w1_1, b1_1, Y2, 480, 4096, 4096);

    // Layer 2: H = Y2 @ W1_2 + b1_2          (480 x 2048, K=4096)
    gemm_kernel<0><<<dim3(32, 8), 256, 0, stream>>>(Y2, w1_2, b1_2, Hb, 480, 2048, 4096);

    // a[g] = prod over pairs of (fwd - rev)
    reduce_prod_kernel<<<dim3(8, 2), 256, 0, stream>>>(Hb, a_buf);

    // mlp2 hidden: t_pre = a @ W2_0 + b2_0 (k-split + atomics)
    init_tpre_kernel<<<dim3(16), 256, 0, stream>>>(b2_0, t_pre);
    mlp2_acc_kernel<<<dim3(8, 8, 2), 256, 0, stream>>>(a_buf, w2_0, t_pre);

    // out = sum_g log|tanh(t_pre[g]) . w2_1 + b2_1|
    finalize_kernel<<<dim3(1), 256, 0, stream>>>(t_pre, w2_1, b2_1, out);
}

// Round 2
// 599.932 us; speedup vs baseline: 1.4924x; 1.4924x over previous
//
#include <hip/hip_runtime.h>
#include <hip/hip_bf16.h>
#include <math.h>

// ---------------------------------------------------------------------------
// Round 2: split-bf16 (bf16x3) MFMA GEMM.
//   fp32 x = hi(bf16) + lo(bf16);  x*w ~= xh*wh + xh*wl + xl*wh  (err ~2^-16)
//   - Activations pre-split into bf16 hi/lo buffers by producer epilogues.
//   - Weights stay fp32 in HBM; converted to bf16 pairs in-register inside
//     the GEMM (no extra HBM traffic; LLC absorbs M-tile re-reads).
//   - Tile: BM=64 x BN=128 x BK=32, 256 thr = 4 waves, 16x16x32 bf16 MFMA.
//     Wave w owns cols [w*32, w*32+32): 4 m-frags x 2 n-frags x 3 products.
// ---------------------------------------------------------------------------

typedef __attribute__((ext_vector_type(8))) short short8;
typedef __attribute__((ext_vector_type(4))) float floatx4;

__device__ __forceinline__ float silu_f(float x) {
    return x / (1.0f + __expf(-x));
}

// RNE split of fp32 into two bf16 (hi + lo)
__device__ __forceinline__ void split2(float x, unsigned short& hi, unsigned short& lo) {
    unsigned u = __float_as_uint(x);
    unsigned r = u + 0x7FFFu + ((u >> 16) & 1u);
    unsigned short h = (unsigned short)(r >> 16);
    float hf = __uint_as_float((unsigned)h << 16);
    float rem = x - hf;
    unsigned u2 = __float_as_uint(rem);
    unsigned r2 = u2 + 0x7FFFu + ((u2 >> 16) & 1u);
    hi = h;
    lo = (unsigned short)(r2 >> 16);
}

// MODE: 0 = raw fp32 out, 1 = +bias fp32 out, 2 = +bias +silu -> bf16 split out
template<int MODE>
__global__ __launch_bounds__(256)
void mfma_gemm(const unsigned short* __restrict__ Ahi,
               const unsigned short* __restrict__ Alo, int lda,
               const float* __restrict__ W, int N,
               const float* __restrict__ bias,
               float* __restrict__ Cf,
               unsigned short* __restrict__ Chi,
               unsigned short* __restrict__ Clo,
               int M, int K)
{
    __shared__ __align__(16) unsigned short As[2][64][40];   // [hi/lo][m][k] k-contig
    __shared__ __align__(16) unsigned short Bs[2][128][40];  // [hi/lo][n][k] k-contig

    const int tid  = threadIdx.x;
    const int lane = tid & 63;
    const int wid  = tid >> 6;
    const int m0 = blockIdx.y * 64;
    const int n0 = blockIdx.x * 128;

    // A staging: thread -> (row, 8k)
    const int ar = tid >> 2;          // 0..63
    const int ak = (tid & 3) * 8;     // 0,8,16,24
    const int agr = m0 + ar;
    const bool a_ok = agr < M;
    const unsigned short* Ah = Ahi + (size_t)agr * lda + ak;
    const unsigned short* Al = Alo + (size_t)agr * lda + ak;

    // W staging: thread -> one n column, 16 consecutive k (two 8-k groups)
    const int wn  = tid & 127;        // 0..127
    const int wk0 = (tid >> 7) * 16;  // 0 or 16
    const float* Wp = W + (size_t)wk0 * N + n0 + wn;

    // frag read offsets
    const int lm = lane & 15;
    const int lk = (lane >> 4) * 8;

    floatx4 acc[4][2];
    #pragma unroll
    for (int ms = 0; ms < 4; ++ms)
        #pragma unroll
        for (int ns = 0; ns < 2; ++ns)
            acc[ms][ns] = (floatx4){0.f, 0.f, 0.f, 0.f};

    const int nsteps = K >> 5;
    for (int s = 0; s < nsteps; ++s) {
        const int k0 = s << 5;
        // ---- global loads (registers; no LDS touched yet) ----
        short8 avh = (short8)(short)0, avl = (short8)(short)0;
        if (a_ok) {
            avh = *(const short8*)(Ah + k0);
            avl = *(const short8*)(Al + k0);
        }
        float wv[16];
        const float* wp = Wp + (size_t)k0 * N;
        #pragma unroll
        for (int j = 0; j < 16; ++j)
            wv[j] = wp[(size_t)j * N];

        short8 bh0, bl0, bh1, bl1;
        #pragma unroll
        for (int j = 0; j < 8; ++j) {
            unsigned short h, l;
            split2(wv[j], h, l);
            bh0[j] = (short)h; bl0[j] = (short)l;
            split2(wv[8 + j], h, l);
            bh1[j] = (short)h; bl1[j] = (short)l;
        }

        __syncthreads();   // prior iteration's frag reads complete
        *(short8*)&As[0][ar][ak] = avh;
        *(short8*)&As[1][ar][ak] = avl;
        *(short8*)&Bs[0][wn][wk0]     = bh0;
        *(short8*)&Bs[1][wn][wk0]     = bl0;
        *(short8*)&Bs[0][wn][wk0 + 8] = bh1;
        *(short8*)&Bs[1][wn][wk0 + 8] = bl1;
        __syncthreads();

        // ---- frags + MFMA ----
        short8 afh[4], afl[4], bfh[2], bfl[2];
        #pragma unroll
        for (int ms = 0; ms < 4; ++ms) {
            afh[ms] = *(const short8*)&As[0][ms * 16 + lm][lk];
            afl[ms] = *(const short8*)&As[1][ms * 16 + lm][lk];
        }
        #pragma unroll
        for (int ns = 0; ns < 2; ++ns) {
            bfh[ns] = *(const short8*)&Bs[0][wid * 32 + ns * 16 + lm][lk];
            bfl[ns] = *(const short8*)&Bs[1][wid * 32 + ns * 16 + lm][lk];
        }
        #pragma unroll
        for (int ms = 0; ms < 4; ++ms) {
            #pragma unroll
            for (int ns = 0; ns < 2; ++ns) {
                acc[ms][ns] = __builtin_amdgcn_mfma_f32_16x16x32_bf16(afh[ms], bfh[ns], acc[ms][ns], 0, 0, 0);
                acc[ms][ns] = __builtin_amdgcn_mfma_f32_16x16x32_bf16(afh[ms], bfl[ns], acc[ms][ns], 0, 0, 0);
                acc[ms][ns] = __builtin_amdgcn_mfma_f32_16x16x32_bf16(afl[ms], bfh[ns], acc[ms][ns], 0, 0, 0);
            }
        }
    }

    // ---- epilogue: C/D layout col=lane&15, row=(lane>>4)*4+reg ----
    const int lr = (lane >> 4) * 4;
    const int lc = lane & 15;
    #pragma unroll
    for (int ns = 0; ns < 2; ++ns) {
        const int gc = n0 + wid * 32 + ns * 16 + lc;
        const float bv = (MODE != 0) ? bias[gc] : 0.0f;
        #pragma unroll
        for (int ms = 0; ms < 4; ++ms) {
            #pragma unroll
            for (int r = 0; r < 4; ++r) {
                const int gr = m0 + ms * 16 + lr + r;
                if (gr < M) {
                    float v = acc[ms][ns][r] + bv;
                    if (MODE == 2) {
                        v = silu_f(v);
                        unsigned short h, l;
                        split2(v, h, l);
                        Chi[(size_t)gr * N + gc] = h;
                        Clo[(size_t)gr * N + gc] = l;
                    } else {
                        Cf[(size_t)gr * N + gc] = v;
                    }
                }
            }
        }
    }
}

// split h_one (32x1024 fp32) into bf16 hi/lo
__global__ __launch_bounds__(256)
void split_h_kernel(const float* __restrict__ h, unsigned short* __restrict__ Hh,
                    unsigned short* __restrict__ Hl) {
    const int idx = blockIdx.x * 256 + threadIdx.x;   // 0..32767
    unsigned short a, b;
    split2(h[idx], a, b);
    Hh[idx] = a;
    Hl[idx] = b;
}

// Y1[r] = silu(P[a(r)] + Q[b(r)] + b1_0)  -> bf16 hi/lo
__global__ __launch_bounds__(256)
void build_y1_kernel(const float* __restrict__ P, const float* __restrict__ Q,
                     const float* __restrict__ b1,
                     unsigned short* __restrict__ Y1h, unsigned short* __restrict__ Y1l) {
    const int r = blockIdx.x;
    const int g = r / 240;
    const int rem = r % 240;
    const int o = rem / 120;
    const int p = rem % 120;
    int i = 0, pp = p, cnt = 15;
    while (pp >= cnt) { pp -= cnt; cnt--; i++; }
    const int j = i + 1 + pp;
    const int ai = g * 16 + (o ? j : i);
    const int bi = g * 16 + (o ? i : j);
    const float4* Pr = (const float4*)(P + (size_t)ai * 4096);
    const float4* Qr = (const float4*)(Q + (size_t)bi * 4096);
    const float4* Br = (const float4*)b1;
    for (int c = threadIdx.x; c < 1024; c += 256) {
        float4 pv = Pr[c], qv = Qr[c], bv = Br[c];
        float s0 = silu_f(pv.x + qv.x + bv.x);
        float s1 = silu_f(pv.y + qv.y + bv.y);
        float s2 = silu_f(pv.z + qv.z + bv.z);
        float s3 = silu_f(pv.w + qv.w + bv.w);
        ushort4 hv, lv;
        split2(s0, hv.x, lv.x);
        split2(s1, hv.y, lv.y);
        split2(s2, hv.z, lv.z);
        split2(s3, hv.w, lv.w);
        *(ushort4*)&Y1h[(size_t)r * 4096 + c * 4] = hv;
        *(ushort4*)&Y1l[(size_t)r * 4096 + c * 4] = lv;
    }
}

// a[g][c] = prod_p (H[g*240+p][c] - H[g*240+120+p][c])
__global__ __launch_bounds__(256)
void reduce_prod_kernel(const float* __restrict__ H, float* __restrict__ a_buf) {
    const int g = blockIdx.y;
    const int c = blockIdx.x * 256 + threadIdx.x;
    const float* base = H + (size_t)g * 240 * 2048 + c;
    float prod = 1.0f;
    for (int p = 0; p < 120; ++p) {
        float f = base[(size_t)p * 2048] - base[(size_t)(120 + p) * 2048];
        prod *= f;
    }
    a_buf[g * 2048 + c] = prod;
}

__global__ __launch_bounds__(256)
void init_tpre_kernel(const float* __restrict__ b2_0, float* __restrict__ t_pre) {
    const int idx = blockIdx.x * 256 + threadIdx.x;
    t_pre[idx] = b2_0[idx & 2047];
}

// t_pre[g][n] += sum_k a[g][k]*W2_0[k][n], both g per block (W read once)
__global__ __launch_bounds__(256)
void mlp2_acc2_kernel(const float* __restrict__ a_buf, const float* __restrict__ W,
                      float* __restrict__ t_pre) {
    __shared__ float a0s[256], a1s[256];
    const int kc = blockIdx.y, nc = blockIdx.x, t = threadIdx.x;
    a0s[t] = a_buf[kc * 256 + t];
    a1s[t] = a_buf[2048 + kc * 256 + t];
    __syncthreads();
    const int n = nc * 256 + t;
    const float* Wp = W + (size_t)(kc * 256) * 2048 + n;
    float s0 = 0.f, s1 = 0.f;
    #pragma unroll 8
    for (int kk = 0; kk < 256; ++kk) {
        float w = Wp[(size_t)kk * 2048];
        s0 = fmaf(a0s[kk], w, s0);
        s1 = fmaf(a1s[kk], w, s1);
    }
    atomicAdd(&t_pre[n], s0);
    atomicAdd(&t_pre[2048 + n], s1);
}

__global__ __launch_bounds__(256)
void finalize_kernel(const float* __restrict__ t_pre, const float* __restrict__ w2_1,
                     const float* __restrict__ b2_1, float* __restrict__ out) {
    __shared__ float red[256];
    const int tid = threadIdx.x;
    float result = 0.0f;
    for (int g = 0; g < 2; ++g) {
        float s = 0.f;
        for (int n = tid; n < 2048; n += 256)
            s += tanhf(t_pre[g * 2048 + n]) * w2_1[n];
        red[tid] = s;
        __syncthreads();
        for (int off = 128; off > 0; off >>= 1) {
            if (tid < off) red[tid] += red[tid + off];
            __syncthreads();
        }
        if (tid == 0) result += logf(fabsf(red[0] + b2_1[0]));
        __syncthreads();
    }
    if (tid == 0) out[0] = result;
}

extern "C" void kernel_launch(void* const* d_in, const int* in_sizes, int n_in,
                              void* d_out, int out_size, void* d_ws, size_t ws_size,
                              hipStream_t stream) {
    const float* h_one = (const float*)d_in[0];   // 32 x 1024
    const float* w1_0  = (const float*)d_in[1];   // 2048 x 4096
    const float* b1_0  = (const float*)d_in[2];   // 4096
    const float* w1_1  = (const float*)d_in[3];   // 4096 x 4096
    const float* b1_1  = (const float*)d_in[4];   // 4096
    const float* w1_2  = (const float*)d_in[5];   // 4096 x 2048
    const float* b1_2  = (const float*)d_in[6];   // 2048
    const float* w2_0  = (const float*)d_in[7];   // 2048 x 2048
    const float* b2_0  = (const float*)d_in[8];   // 2048
    const float* w2_1  = (const float*)d_in[9];   // 2048
    const float* b2_1  = (const float*)d_in[10];  // 1
    float* out = (float*)d_out;

    char* ws = (char*)d_ws;
    unsigned short* Hh  = (unsigned short*)ws;                 ws += (size_t)32 * 1024 * 2;
    unsigned short* Hl  = (unsigned short*)ws;                 ws += (size_t)32 * 1024 * 2;
    float*          P   = (float*)ws;                          ws += (size_t)32 * 4096 * 4;
    float*          Q   = (float*)ws;                          ws += (size_t)32 * 4096 * 4;
    unsigned short* Y1h = (unsigned short*)ws;                 ws += (size_t)480 * 4096 * 2;
    unsigned short* Y1l = (unsigned short*)ws;                 ws += (size_t)480 * 4096 * 2;
    unsigned short* Y2h = (unsigned short*)ws;                 ws += (size_t)480 * 4096 * 2;
    unsigned short* Y2l = (unsigned short*)ws;                 ws += (size_t)480 * 4096 * 2;
    float*          Hb  = (float*)ws;                          ws += (size_t)480 * 2048 * 4;
    float*          a_buf = (float*)ws;                        ws += (size_t)2 * 2048 * 4;
    float*          t_pre = (float*)ws;                        ws += (size_t)2 * 2048 * 4;

    // split h_one into bf16 hi/lo
    split_h_kernel<<<128, 256, 0, stream>>>(h_one, Hh, Hl);

    // P = h @ W1_0[:1024], Q = h @ W1_0[1024:]   (M=32, N=4096, K=1024)
    mfma_gemm<0><<<dim3(32, 1), 256, 0, stream>>>(Hh, Hl, 1024, w1_0, 4096,
                                                  nullptr, P, nullptr, nullptr, 32, 1024);
    mfma_gemm<0><<<dim3(32, 1), 256, 0, stream>>>(Hh, Hl, 1024, w1_0 + (size_t)1024 * 4096, 4096,
                                                  nullptr, Q, nullptr, nullptr, 32, 1024);

    // Y1 = silu(P[i]+Q[j]+b) pairs -> bf16 split
    build_y1_kernel<<<480, 256, 0, stream>>>(P, Q, b1_0, Y1h, Y1l);

    // Y2 = silu(Y1 @ W1_1 + b1_1) -> bf16 split  (M=480, N=4096, K=4096)
    mfma_gemm<2><<<dim3(32, 8), 256, 0, stream>>>(Y1h, Y1l, 4096, w1_1, 4096,
                                                  b1_1, nullptr, Y2h, Y2l, 480, 4096);

    // Hb = Y2 @ W1_2 + b1_2  (M=480, N=2048, K=4096) fp32 out
    mfma_gemm<1><<<dim3(16, 8), 256, 0, stream>>>(Y2h, Y2l, 4096, w1_2, 2048,
                                                  b1_2, Hb, nullptr, nullptr, 480, 4096);

    // a[g] = prod over pairs
    reduce_prod_kernel<<<dim3(8, 2), 256, 0, stream>>>(Hb, a_buf);

    // mlp2 hidden
    init_tpre_kernel<<<16, 256, 0, stream>>>(b2_0, t_pre);
    mlp2_acc2_kernel<<<dim3(8, 8), 256, 0, stream>>>(a_buf, w2_0, t_pre);

    // out
    finalize_kernel<<<1, 256, 0, stream>>>(t_pre, w2_1, b2_1, out);
}

// Round 3
// 523.266 us; speedup vs baseline: 1.7110x; 1.1465x over previous
//
#include <hip/hip_runtime.h>
#include <hip/hip_bf16.h>
#include <math.h>

// ---------------------------------------------------------------------------
// Round 3: LDS-free split-bf16 MFMA GEMM with pre-transposed/pre-split weights.
//   - transpose_split: W[K][N] fp32 -> Wh[N][K], Wl[N][K] bf16 (k-contiguous)
//   - GEMM: direct global->register MFMA fragments (short8 = 8 contig k),
//     64x64 per wave, 4 indep waves/block, K-split partials, no LDS/barriers.
//   - reduce kernels fuse partial-sum + bias + silu + bf16-split.
// ---------------------------------------------------------------------------

typedef __attribute__((ext_vector_type(8))) short short8;
typedef __attribute__((ext_vector_type(4))) float floatx4;

__device__ __forceinline__ float silu_f(float x) {
    return x / (1.0f + __expf(-x));
}

// RNE split of fp32 into two bf16 (hi + lo)
__device__ __forceinline__ void split2(float x, unsigned short& hi, unsigned short& lo) {
    unsigned u = __float_as_uint(x);
    unsigned r = u + 0x7FFFu + ((u >> 16) & 1u);
    unsigned short h = (unsigned short)(r >> 16);
    float hf = __uint_as_float((unsigned)h << 16);
    float rem = x - hf;
    unsigned u2 = __float_as_uint(rem);
    unsigned r2 = u2 + 0x7FFFu + ((u2 >> 16) & 1u);
    hi = h;
    lo = (unsigned short)(r2 >> 16);
}

// ---------------- transpose + split: W[K][N] f32 -> Th[N][K], Tl[N][K] bf16
__global__ __launch_bounds__(256)
void transpose_split(const float* __restrict__ W, unsigned short* __restrict__ Th,
                     unsigned short* __restrict__ Tl, int K, int N) {
    __shared__ float tile[32][33];
    const int t = threadIdx.x;
    const int n0 = blockIdx.x * 32;
    const int k0 = blockIdx.y * 32;
    const int r  = t >> 3;          // 0..31
    const int c4 = (t & 7) * 4;     // 0..28
    float4 v = *(const float4*)&W[(size_t)(k0 + r) * N + n0 + c4];
    tile[r][c4 + 0] = v.x;
    tile[r][c4 + 1] = v.y;
    tile[r][c4 + 2] = v.z;
    tile[r][c4 + 3] = v.w;
    __syncthreads();
    // write transposed: Th[n0+r][k0+c4 .. +3] = tile[c4+i][r]
    ushort4 hv, lv;
    split2(tile[c4 + 0][r], hv.x, lv.x);
    split2(tile[c4 + 1][r], hv.y, lv.y);
    split2(tile[c4 + 2][r], hv.z, lv.z);
    split2(tile[c4 + 3][r], hv.w, lv.w);
    *(ushort4*)&Th[(size_t)(n0 + r) * K + k0 + c4] = hv;
    *(ushort4*)&Tl[(size_t)(n0 + r) * K + k0 + c4] = lv;
}

// ---------------- LDS-free MFMA GEMM, wave tile 64x64, K-split partials
__device__ __forceinline__ void load_set(
    const unsigned short* __restrict__ Ah, const unsigned short* __restrict__ Al,
    const unsigned short* __restrict__ Bh, const unsigned short* __restrict__ Bl,
    const unsigned aoff[4], const unsigned boff[4], int koff,
    short8 (&ah)[4], short8 (&al)[4], short8 (&bh)[4], short8 (&bl)[4])
{
    #pragma unroll
    for (int i = 0; i < 4; ++i) {
        ah[i] = *(const short8*)(Ah + aoff[i] + koff);
        al[i] = *(const short8*)(Al + aoff[i] + koff);
        bh[i] = *(const short8*)(Bh + boff[i] + koff);
        bl[i] = *(const short8*)(Bl + boff[i] + koff);
    }
}

__device__ __forceinline__ void mfma_set(
    const short8 (&ah)[4], const short8 (&al)[4],
    const short8 (&bh)[4], const short8 (&bl)[4],
    floatx4 (&acc)[4][4])
{
    #pragma unroll
    for (int ms = 0; ms < 4; ++ms)
        #pragma unroll
        for (int ns = 0; ns < 4; ++ns)
            acc[ms][ns] = __builtin_amdgcn_mfma_f32_16x16x32_bf16(ah[ms], bh[ns], acc[ms][ns], 0, 0, 0);
    #pragma unroll
    for (int ms = 0; ms < 4; ++ms)
        #pragma unroll
        for (int ns = 0; ns < 4; ++ns)
            acc[ms][ns] = __builtin_amdgcn_mfma_f32_16x16x32_bf16(al[ms], bh[ns], acc[ms][ns], 0, 0, 0);
    #pragma unroll
    for (int ms = 0; ms < 4; ++ms)
        #pragma unroll
        for (int ns = 0; ns < 4; ++ns)
            acc[ms][ns] = __builtin_amdgcn_mfma_f32_16x16x32_bf16(ah[ms], bl[ns], acc[ms][ns], 0, 0, 0);
}

// grid: (N/256, Mpad/64, S).  Block = 4 waves, wave w covers 64 n-cols.
// Cpart[z][Mpad][N] fp32 raw partial over k chunk [z*kc, (z+1)*kc).
__global__ __launch_bounds__(256, 2)
void mfma_gemm_df(const unsigned short* __restrict__ Ah,
                  const unsigned short* __restrict__ Al, int astride,
                  const unsigned short* __restrict__ Bh,
                  const unsigned short* __restrict__ Bl, int bstride,
                  float* __restrict__ Cpart, int N, int Mpad, int kc)
{
    const int tid  = threadIdx.x;
    const int lane = tid & 63;
    const int wid  = tid >> 6;
    const int n0 = blockIdx.x * 256 + wid * 64;
    const int m0 = blockIdx.y * 64;
    const int kbase = blockIdx.z * kc;
    const int lm = lane & 15;
    const int lk = (lane >> 4) * 8;

    unsigned aoff[4], boff[4];
    #pragma unroll
    for (int i = 0; i < 4; ++i) {
        aoff[i] = (unsigned)(m0 + i * 16 + lm) * astride + kbase + lk;
        boff[i] = (unsigned)(n0 + i * 16 + lm) * bstride + kbase + lk;
    }

    floatx4 acc[4][4];
    #pragma unroll
    for (int ms = 0; ms < 4; ++ms)
        #pragma unroll
        for (int ns = 0; ns < 4; ++ns)
            acc[ms][ns] = (floatx4){0.f, 0.f, 0.f, 0.f};

    short8 a0h[4], a0l[4], b0h[4], b0l[4];
    short8 a1h[4], a1l[4], b1h[4], b1l[4];

    const int S = kc >> 5;   // k-steps of 32 (S is even for all our shapes)
    load_set(Ah, Al, Bh, Bl, aoff, boff, 0, a0h, a0l, b0h, b0l);
    for (int s = 0; s + 1 < S; s += 2) {
        load_set(Ah, Al, Bh, Bl, aoff, boff, (s + 1) << 5, a1h, a1l, b1h, b1l);
        mfma_set(a0h, a0l, b0h, b0l, acc);
        if (s + 2 < S)
            load_set(Ah, Al, Bh, Bl, aoff, boff, (s + 2) << 5, a0h, a0l, b0h, b0l);
        mfma_set(a1h, a1l, b1h, b1l, acc);
    }

    float* Cp = Cpart + (size_t)blockIdx.z * Mpad * N;
    const int lr = (lane >> 4) * 4;
    #pragma unroll
    for (int ms = 0; ms < 4; ++ms)
        #pragma unroll
        for (int ns = 0; ns < 4; ++ns)
            #pragma unroll
            for (int r = 0; r < 4; ++r)
                Cp[(size_t)(m0 + ms * 16 + lr + r) * N + n0 + ns * 16 + lm] = acc[ms][ns][r];
}

// ---------------- small kernels ----------------
__global__ __launch_bounds__(256)
void split_h_kernel(const float* __restrict__ h, unsigned short* __restrict__ Hh,
                    unsigned short* __restrict__ Hl) {
    const int idx = blockIdx.x * 256 + threadIdx.x;   // 0..32767
    unsigned short a, b;
    split2(h[idx], a, b);
    Hh[idx] = a;
    Hl[idx] = b;
}

// Y1[r] = silu(P[a(r)] + Q[b(r)] + b1_0) -> bf16 hi/lo.  P/Q = sum of 2 k-chunks.
__global__ __launch_bounds__(256)
void build_y1_kernel(const float* __restrict__ Pp, const float* __restrict__ Qp,
                     const float* __restrict__ b1,
                     unsigned short* __restrict__ Y1h, unsigned short* __restrict__ Y1l) {
    const int r = blockIdx.x;
    const int g = r / 240;
    const int rem = r % 240;
    const int o = rem / 120;
    const int p = rem % 120;
    int i = 0, pp = p, cnt = 15;
    while (pp >= cnt) { pp -= cnt; cnt--; i++; }
    const int j = i + 1 + pp;
    const int ai = g * 16 + (o ? j : i);
    const int bi = g * 16 + (o ? i : j);
    const size_t chunk4 = (size_t)64 * 4096 / 4;
    const float4* Pr0 = (const float4*)(Pp + (size_t)ai * 4096);
    const float4* Qr0 = (const float4*)(Qp + (size_t)bi * 4096);
    const float4* Br  = (const float4*)b1;
    for (int c = threadIdx.x; c < 1024; c += 256) {
        float4 p0 = Pr0[c], p1 = Pr0[c + chunk4];
        float4 q0 = Qr0[c], q1 = Qr0[c + chunk4];
        float4 bv = Br[c];
        float s0 = silu_f(p0.x + p1.x + q0.x + q1.x + bv.x);
        float s1 = silu_f(p0.y + p1.y + q0.y + q1.y + bv.y);
        float s2 = silu_f(p0.z + p1.z + q0.z + q1.z + bv.z);
        float s3 = silu_f(p0.w + p1.w + q0.w + q1.w + bv.w);
        ushort4 hv, lv;
        split2(s0, hv.x, lv.x);
        split2(s1, hv.y, lv.y);
        split2(s2, hv.z, lv.z);
        split2(s3, hv.w, lv.w);
        *(ushort4*)&Y1h[(size_t)r * 4096 + c * 4] = hv;
        *(ushort4*)&Y1l[(size_t)r * 4096 + c * 4] = lv;
    }
}

// Y2 = silu(sum of 4 partials + b1_1) -> bf16 split.  [512][4096]
__global__ __launch_bounds__(256)
void reduce4_silu_split(const float* __restrict__ Part, const float* __restrict__ bias,
                        unsigned short* __restrict__ Yh, unsigned short* __restrict__ Yl) {
    const size_t idx = (size_t)blockIdx.x * 256 + threadIdx.x;  // float4 index
    const size_t stride4 = (size_t)512 * 4096 / 4;
    const float4* p = (const float4*)Part;
    float4 v0 = p[idx], v1 = p[idx + stride4], v2 = p[idx + 2 * stride4], v3 = p[idx + 3 * stride4];
    const int col = (int)((idx * 4) & 4095);
    float4 b = *(const float4*)&bias[col];
    float s0 = silu_f(v0.x + v1.x + v2.x + v3.x + b.x);
    float s1 = silu_f(v0.y + v1.y + v2.y + v3.y + b.y);
    float s2 = silu_f(v0.z + v1.z + v2.z + v3.z + b.z);
    float s3 = silu_f(v0.w + v1.w + v2.w + v3.w + b.w);
    ushort4 hv, lv;
    split2(s0, hv.x, lv.x);
    split2(s1, hv.y, lv.y);
    split2(s2, hv.z, lv.z);
    split2(s3, hv.w, lv.w);
    *(ushort4*)&Yh[idx * 4] = hv;
    *(ushort4*)&Yl[idx * 4] = lv;
}

// Hb = sum of 8 partials + b1_2  (fp32)  [512][2048]
__global__ __launch_bounds__(256)
void reduce8_bias(const float* __restrict__ Part, const float* __restrict__ bias,
                  float* __restrict__ Hb) {
    const size_t idx = (size_t)blockIdx.x * 256 + threadIdx.x;  // float4 index
    const size_t stride4 = (size_t)512 * 2048 / 4;
    const float4* p = (const float4*)Part;
    float4 s = p[idx];
    #pragma unroll
    for (int c = 1; c < 8; ++c) {
        float4 v = p[idx + c * stride4];
        s.x += v.x; s.y += v.y; s.z += v.z; s.w += v.w;
    }
    const int col = (int)((idx * 4) & 2047);
    float4 b = *(const float4*)&bias[col];
    s.x += b.x; s.y += b.y; s.z += b.z; s.w += b.w;
    *(float4*)&Hb[idx * 4] = s;
}

// a[g][c] = prod_p (H[g*240+p][c] - H[g*240+120+p][c])
__global__ __launch_bounds__(256)
void reduce_prod_kernel(const float* __restrict__ H, float* __restrict__ a_buf) {
    const int g = blockIdx.y;
    const int c = blockIdx.x * 256 + threadIdx.x;
    const float* base = H + (size_t)g * 240 * 2048 + c;
    float prod = 1.0f;
    for (int p = 0; p < 120; ++p) {
        float f = base[(size_t)p * 2048] - base[(size_t)(120 + p) * 2048];
        prod *= f;
    }
    a_buf[g * 2048 + c] = prod;
}

__global__ __launch_bounds__(256)
void init_tpre_kernel(const float* __restrict__ b2_0, float* __restrict__ t_pre) {
    const int idx = blockIdx.x * 256 + threadIdx.x;
    t_pre[idx] = b2_0[idx & 2047];
}

__global__ __launch_bounds__(256)
void mlp2_acc2_kernel(const float* __restrict__ a_buf, const float* __restrict__ W,
                      float* __restrict__ t_pre) {
    __shared__ float a0s[256], a1s[256];
    const int kc = blockIdx.y, nc = blockIdx.x, t = threadIdx.x;
    a0s[t] = a_buf[kc * 256 + t];
    a1s[t] = a_buf[2048 + kc * 256 + t];
    __syncthreads();
    const int n = nc * 256 + t;
    const float* Wp = W + (size_t)(kc * 256) * 2048 + n;
    float s0 = 0.f, s1 = 0.f;
    #pragma unroll 8
    for (int kk = 0; kk < 256; ++kk) {
        float w = Wp[(size_t)kk * 2048];
        s0 = fmaf(a0s[kk], w, s0);
        s1 = fmaf(a1s[kk], w, s1);
    }
    atomicAdd(&t_pre[n], s0);
    atomicAdd(&t_pre[2048 + n], s1);
}

__global__ __launch_bounds__(256)
void finalize_kernel(const float* __restrict__ t_pre, const float* __restrict__ w2_1,
                     const float* __restrict__ b2_1, float* __restrict__ out) {
    __shared__ float red[256];
    const int tid = threadIdx.x;
    float result = 0.0f;
    for (int g = 0; g < 2; ++g) {
        float s = 0.f;
        for (int n = tid; n < 2048; n += 256)
            s += tanhf(t_pre[g * 2048 + n]) * w2_1[n];
        red[tid] = s;
        __syncthreads();
        for (int off = 128; off > 0; off >>= 1) {
            if (tid < off) red[tid] += red[tid + off];
            __syncthreads();
        }
        if (tid == 0) result += logf(fabsf(red[0] + b2_1[0]));
        __syncthreads();
    }
    if (tid == 0) out[0] = result;
}

extern "C" void kernel_launch(void* const* d_in, const int* in_sizes, int n_in,
                              void* d_out, int out_size, void* d_ws, size_t ws_size,
                              hipStream_t stream) {
    const float* h_one = (const float*)d_in[0];   // 32 x 1024
    const float* w1_0  = (const float*)d_in[1];   // 2048 x 4096
    const float* b1_0  = (const float*)d_in[2];   // 4096
    const float* w1_1  = (const float*)d_in[3];   // 4096 x 4096
    const float* b1_1  = (const float*)d_in[4];   // 4096
    const float* w1_2  = (const float*)d_in[5];   // 4096 x 2048
    const float* b1_2  = (const float*)d_in[6];   // 2048
    const float* w2_0  = (const float*)d_in[7];   // 2048 x 2048
    const float* b2_0  = (const float*)d_in[8];   // 2048
    const float* w2_1  = (const float*)d_in[9];   // 2048
    const float* b2_1  = (const float*)d_in[10];  // 1
    float* out = (float*)d_out;

    char* ws = (char*)d_ws;
    // regA: holds W11t during L1, then W12t during L2 (67.2 MB)
    unsigned short* W11t_h = (unsigned short*)ws;
    unsigned short* W11t_l = W11t_h + (size_t)4096 * 4096;
    unsigned short* W12t_h = (unsigned short*)ws;                 // after L1
    unsigned short* W12t_l = W12t_h + (size_t)2048 * 4096;
    ws += (size_t)4096 * 4096 * 2 * 2;
    // regB: W10t during P/Q, then PartL1 / PartL2 (33.55 MB)
    unsigned short* W10t_h = (unsigned short*)ws;
    unsigned short* W10t_l = W10t_h + (size_t)4096 * 2048;
    float*          PartL1 = (float*)W10t_h;                      // 4 x 512 x 4096
    float*          PartL2 = (float*)W10t_h;                      // 8 x 512 x 2048
    ws += (size_t)4096 * 2048 * 2 * 2;
    unsigned short* Hh  = (unsigned short*)ws;  ws += (size_t)64 * 1024 * 2;
    unsigned short* Hl  = (unsigned short*)ws;  ws += (size_t)64 * 1024 * 2;
    float* Pp  = (float*)ws;                    ws += (size_t)2 * 64 * 4096 * 4;
    float* Qp  = (float*)ws;                    ws += (size_t)2 * 64 * 4096 * 4;
    unsigned short* Y1h = (unsigned short*)ws;  ws += (size_t)512 * 4096 * 2;
    unsigned short* Y1l = (unsigned short*)ws;  ws += (size_t)512 * 4096 * 2;
    unsigned short* Y2h = (unsigned short*)ws;  ws += (size_t)512 * 4096 * 2;
    unsigned short* Y2l = (unsigned short*)ws;  ws += (size_t)512 * 4096 * 2;
    float* Hb    = (float*)ws;                  ws += (size_t)512 * 2048 * 4;
    float* a_buf = (float*)ws;                  ws += (size_t)2 * 2048 * 4;
    float* t_pre = (float*)ws;                  ws += (size_t)2 * 2048 * 4;

    // --- stage 0: W1_0 transpose+split; h split; P/Q GEMMs; Y1 build ---
    transpose_split<<<dim3(128, 64), 256, 0, stream>>>(w1_0, W10t_h, W10t_l, 2048, 4096);
    split_h_kernel<<<128, 256, 0, stream>>>(h_one, Hh, Hl);
    // P: k in [0,1024) of W10t[N=4096][K=2048]; Q: column offset +1024
    mfma_gemm_df<<<dim3(16, 1, 2), 256, 0, stream>>>(Hh, Hl, 1024, W10t_h, W10t_l, 2048,
                                                     Pp, 4096, 64, 512);
    mfma_gemm_df<<<dim3(16, 1, 2), 256, 0, stream>>>(Hh, Hl, 1024, W10t_h + 1024, W10t_l + 1024, 2048,
                                                     Qp, 4096, 64, 512);
    build_y1_kernel<<<480, 256, 0, stream>>>(Pp, Qp, b1_0, Y1h, Y1l);

    // --- stage 1: Y2 = silu(Y1 @ W1_1 + b1_1) ---
    transpose_split<<<dim3(128, 128), 256, 0, stream>>>(w1_1, W11t_h, W11t_l, 4096, 4096);
    mfma_gemm_df<<<dim3(16, 8, 4), 256, 0, stream>>>(Y1h, Y1l, 4096, W11t_h, W11t_l, 4096,
                                                     PartL1, 4096, 512, 1024);
    reduce4_silu_split<<<2048, 256, 0, stream>>>(PartL1, b1_1, Y2h, Y2l);

    // --- stage 2: Hb = Y2 @ W1_2 + b1_2 ---
    transpose_split<<<dim3(64, 128), 256, 0, stream>>>(w1_2, W12t_h, W12t_l, 4096, 2048);
    mfma_gemm_df<<<dim3(8, 8, 8), 256, 0, stream>>>(Y2h, Y2l, 4096, W12t_h, W12t_l, 4096,
                                                    PartL2, 2048, 512, 512);
    reduce8_bias<<<1024, 256, 0, stream>>>(PartL2, b1_2, Hb);

    // --- tail ---
    reduce_prod_kernel<<<dim3(8, 2), 256, 0, stream>>>(Hb, a_buf);
    init_tpre_kernel<<<16, 256, 0, stream>>>(b2_0, t_pre);
    mlp2_acc2_kernel<<<dim3(8, 8), 256, 0, stream>>>(a_buf, w2_0, t_pre);
    finalize_kernel<<<1, 256, 0, stream>>>(t_pre, w2_1, b2_1, out);
}

// Round 4
// 416.632 us; speedup vs baseline: 2.1489x; 1.2559x over previous
//
#include <hip/hip_runtime.h>
#include <hip/hip_bf16.h>
#include <math.h>

// ---------------------------------------------------------------------------
// Round 4: m97-style LDS-staged split-bf16 MFMA GEMM.
//   - gemm128: 128x128 tile, BK=32, 4 waves (each 64x64, 4x4 frags, 3 MFMA
//     products per frag pair), global_load_lds width-16 staging of A-hi/lo
//     and B-hi/lo planes, XOR chunk swizzle for conflict-free ds_read_b128.
//   - One fused transpose+split kernel for all three weights.
//   - P/Q (tiny M=64) keeps the round-3 LDS-free kernel.
// ---------------------------------------------------------------------------

typedef __attribute__((ext_vector_type(8))) short short8;
typedef __attribute__((ext_vector_type(4))) float floatx4;

#define AS1 __attribute__((address_space(1)))
#define AS3 __attribute__((address_space(3)))
#define GLD16(g, l) __builtin_amdgcn_global_load_lds((AS1 const unsigned int*)(g), (AS3 unsigned int*)(l), 16, 0, 0)

__device__ __forceinline__ float silu_f(float x) {
    return x / (1.0f + __expf(-x));
}

// RNE split of fp32 into two bf16 (hi + lo)
__device__ __forceinline__ void split2(float x, unsigned short& hi, unsigned short& lo) {
    unsigned u = __float_as_uint(x);
    unsigned r = u + 0x7FFFu + ((u >> 16) & 1u);
    unsigned short h = (unsigned short)(r >> 16);
    float hf = __uint_as_float((unsigned)h << 16);
    float rem = x - hf;
    unsigned u2 = __float_as_uint(rem);
    unsigned r2 = u2 + 0x7FFFu + ((u2 >> 16) & 1u);
    hi = h;
    lo = (unsigned short)(r2 >> 16);
}

// ---------------- fused transpose+split for w1_0 / w1_1 / w1_2 -------------
// W[K][N] f32 -> Th[N][K], Tl[N][K] bf16 (k-contiguous)
__global__ __launch_bounds__(256)
void transpose_split_all(const float* __restrict__ w10, const float* __restrict__ w11,
                         const float* __restrict__ w12,
                         unsigned short* __restrict__ t10h, unsigned short* __restrict__ t10l,
                         unsigned short* __restrict__ t11h, unsigned short* __restrict__ t11l,
                         unsigned short* __restrict__ t12h, unsigned short* __restrict__ t12l) {
    __shared__ float tile[32][33];
    int id = blockIdx.x;
    const float* W;
    unsigned short *Th, *Tl;
    int K, N, nt, kt;
    if (id < 8192)        { W = w10; Th = t10h; Tl = t10l; K = 2048; N = 4096; nt = id & 127; kt = id >> 7; }
    else if (id < 24576)  { id -= 8192;  W = w11; Th = t11h; Tl = t11l; K = 4096; N = 4096; nt = id & 127; kt = id >> 7; }
    else                  { id -= 24576; W = w12; Th = t12h; Tl = t12l; K = 4096; N = 2048; nt = id & 63;  kt = id >> 6; }
    const int t  = threadIdx.x;
    const int n0 = nt * 32;
    const int k0 = kt * 32;
    const int r  = t >> 3;          // 0..31
    const int c4 = (t & 7) * 4;     // 0..28
    float4 v = *(const float4*)&W[(size_t)(k0 + r) * N + n0 + c4];
    tile[r][c4 + 0] = v.x;
    tile[r][c4 + 1] = v.y;
    tile[r][c4 + 2] = v.z;
    tile[r][c4 + 3] = v.w;
    __syncthreads();
    ushort4 hv, lv;
    split2(tile[c4 + 0][r], hv.x, lv.x);
    split2(tile[c4 + 1][r], hv.y, lv.y);
    split2(tile[c4 + 2][r], hv.z, lv.z);
    split2(tile[c4 + 3][r], hv.w, lv.w);
    *(ushort4*)&Th[(size_t)(n0 + r) * K + k0 + c4] = hv;
    *(ushort4*)&Tl[(size_t)(n0 + r) * K + k0 + c4] = lv;
}

// ---------------- m97-style LDS-staged GEMM, 128x128 tile ------------------
// A(hi/lo)[M][K], B(hi/lo)[N][K] bf16 k-contig. Cpart[z][Mtot][N] fp32.
// grid: (N/128, Mtot/128, Z), kc = K/Z (multiple of 32).
__global__ __launch_bounds__(256, 2)
void gemm128(const unsigned short* __restrict__ Ah, const unsigned short* __restrict__ Al,
             const unsigned short* __restrict__ Bh, const unsigned short* __restrict__ Bl,
             int K, float* __restrict__ Cpart, int N, int Mtot, int kc)
{
    __shared__ __align__(16) unsigned short As[2][128][32];   // [hi/lo][row][k] swizzled chunks
    __shared__ __align__(16) unsigned short Bs[2][128][32];

    const int tid  = threadIdx.x;
    const int lane = tid & 63;
    const int wid  = tid >> 6;
    const int n0 = blockIdx.x * 128;
    const int m0 = blockIdx.y * 128;
    const int kbase = blockIdx.z * kc;

    // ---- staging setup: wave w stages LDS rows [w*32, w*32+32) of each plane
    const int srow   = wid * 32 + (lane >> 2);              // LDS row (first 16-row inst)
    const int schunk = (lane & 3) ^ ((srow >> 1) & 3);      // swizzled source k-chunk
    // (row+16) has the same swizzle: ((srow+16)>>1)&3 == (srow>>1)&3
    const unsigned short* gA0h = Ah + (size_t)(m0 + srow) * K + kbase + schunk * 8;
    const unsigned short* gA1h = gA0h + (size_t)16 * K;
    const unsigned short* gA0l = Al + (size_t)(m0 + srow) * K + kbase + schunk * 8;
    const unsigned short* gA1l = gA0l + (size_t)16 * K;
    const unsigned short* gB0h = Bh + (size_t)(n0 + srow) * K + kbase + schunk * 8;
    const unsigned short* gB1h = gB0h + (size_t)16 * K;
    const unsigned short* gB0l = Bl + (size_t)(n0 + srow) * K + kbase + schunk * 8;
    const unsigned short* gB1l = gB0l + (size_t)16 * K;
    unsigned short* lA0h = &As[0][wid * 32][0];
    unsigned short* lA1h = &As[0][wid * 32 + 16][0];
    unsigned short* lA0l = &As[1][wid * 32][0];
    unsigned short* lA1l = &As[1][wid * 32 + 16][0];
    unsigned short* lB0h = &Bs[0][wid * 32][0];
    unsigned short* lB1h = &Bs[0][wid * 32 + 16][0];
    unsigned short* lB0l = &Bs[1][wid * 32][0];
    unsigned short* lB1l = &Bs[1][wid * 32 + 16][0];

    // ---- frag-read setup: wave grid 2x2, wave = (mhalf, nhalf)
    const int mhalf = wid >> 1;
    const int nhalf = wid & 1;
    const int lm = lane & 15;
    const int q  = lane >> 4;          // k-chunk 0..3
    // LDS byte offsets for the 4 m-frags / n-frags (hi plane; lo = +8 KB)
    int aoffs[4], boffs[4];
    #pragma unroll
    for (int f = 0; f < 4; ++f) {
        int arow = mhalf * 64 + f * 16 + lm;
        int aslot = q ^ ((arow >> 1) & 3);
        aoffs[f] = arow * 32 + aslot * 8;           // in ushort units
        int brow = nhalf * 64 + f * 16 + lm;
        int bslot = q ^ ((brow >> 1) & 3);
        boffs[f] = brow * 32 + bslot * 8;
    }
    const unsigned short* AsF = &As[0][0][0];
    const unsigned short* BsF = &Bs[0][0][0];

    floatx4 acc[4][4];
    #pragma unroll
    for (int ms = 0; ms < 4; ++ms)
        #pragma unroll
        for (int ns = 0; ns < 4; ++ns)
            acc[ms][ns] = (floatx4){0.f, 0.f, 0.f, 0.f};

    const int S = kc >> 5;
    for (int s = 0; s < S; ++s) {
        const int ko = s << 5;   // element offset within chunk
        __syncthreads();         // previous iteration's frag reads complete
        GLD16(gA0h + ko, lA0h);
        GLD16(gA1h + ko, lA1h);
        GLD16(gA0l + ko, lA0l);
        GLD16(gA1l + ko, lA1l);
        GLD16(gB0h + ko, lB0h);
        GLD16(gB1h + ko, lB1h);
        GLD16(gB0l + ko, lB0l);
        GLD16(gB1l + ko, lB1l);
        __syncthreads();         // tiles resident

        short8 afh[4], afl[4], bfh[4], bfl[4];
        #pragma unroll
        for (int f = 0; f < 4; ++f) {
            afh[f] = *(const short8*)(AsF + aoffs[f]);
            afl[f] = *(const short8*)(AsF + 4096 + aoffs[f]);
            bfh[f] = *(const short8*)(BsF + boffs[f]);
            bfl[f] = *(const short8*)(BsF + 4096 + boffs[f]);
        }
        #pragma unroll
        for (int ms = 0; ms < 4; ++ms)
            #pragma unroll
            for (int ns = 0; ns < 4; ++ns)
                acc[ms][ns] = __builtin_amdgcn_mfma_f32_16x16x32_bf16(afh[ms], bfh[ns], acc[ms][ns], 0, 0, 0);
        #pragma unroll
        for (int ms = 0; ms < 4; ++ms)
            #pragma unroll
            for (int ns = 0; ns < 4; ++ns)
                acc[ms][ns] = __builtin_amdgcn_mfma_f32_16x16x32_bf16(afl[ms], bfh[ns], acc[ms][ns], 0, 0, 0);
        #pragma unroll
        for (int ms = 0; ms < 4; ++ms)
            #pragma unroll
            for (int ns = 0; ns < 4; ++ns)
                acc[ms][ns] = __builtin_amdgcn_mfma_f32_16x16x32_bf16(afh[ms], bfl[ns], acc[ms][ns], 0, 0, 0);
    }

    float* Cp = Cpart + (size_t)blockIdx.z * Mtot * N;
    const int lr = (lane >> 4) * 4;
    #pragma unroll
    for (int ms = 0; ms < 4; ++ms)
        #pragma unroll
        for (int ns = 0; ns < 4; ++ns)
            #pragma unroll
            for (int r = 0; r < 4; ++r)
                Cp[(size_t)(m0 + mhalf * 64 + ms * 16 + lr + r) * N + n0 + nhalf * 64 + ns * 16 + lm] = acc[ms][ns][r];
}

// ---------------- round-3 LDS-free GEMM (kept for tiny P/Q) ----------------
__device__ __forceinline__ void load_set(
    const unsigned short* __restrict__ Ah, const unsigned short* __restrict__ Al,
    const unsigned short* __restrict__ Bh, const unsigned short* __restrict__ Bl,
    const unsigned aoff[4], const unsigned boff[4], int koff,
    short8 (&ah)[4], short8 (&al)[4], short8 (&bh)[4], short8 (&bl)[4])
{
    #pragma unroll
    for (int i = 0; i < 4; ++i) {
        ah[i] = *(const short8*)(Ah + aoff[i] + koff);
        al[i] = *(const short8*)(Al + aoff[i] + koff);
        bh[i] = *(const short8*)(Bh + boff[i] + koff);
        bl[i] = *(const short8*)(Bl + boff[i] + koff);
    }
}

__device__ __forceinline__ void mfma_set(
    const short8 (&ah)[4], const short8 (&al)[4],
    const short8 (&bh)[4], const short8 (&bl)[4],
    floatx4 (&acc)[4][4])
{
    #pragma unroll
    for (int ms = 0; ms < 4; ++ms)
        #pragma unroll
        for (int ns = 0; ns < 4; ++ns)
            acc[ms][ns] = __builtin_amdgcn_mfma_f32_16x16x32_bf16(ah[ms], bh[ns], acc[ms][ns], 0, 0, 0);
    #pragma unroll
    for (int ms = 0; ms < 4; ++ms)
        #pragma unroll
        for (int ns = 0; ns < 4; ++ns)
            acc[ms][ns] = __builtin_amdgcn_mfma_f32_16x16x32_bf16(al[ms], bh[ns], acc[ms][ns], 0, 0, 0);
    #pragma unroll
    for (int ms = 0; ms < 4; ++ms)
        #pragma unroll
        for (int ns = 0; ns < 4; ++ns)
            acc[ms][ns] = __builtin_amdgcn_mfma_f32_16x16x32_bf16(ah[ms], bl[ns], acc[ms][ns], 0, 0, 0);
}

__global__ __launch_bounds__(256, 2)
void mfma_gemm_df(const unsigned short* __restrict__ Ah,
                  const unsigned short* __restrict__ Al, int astride,
                  const unsigned short* __restrict__ Bh,
                  const unsigned short* __restrict__ Bl, int bstride,
                  float* __restrict__ Cpart, int N, int Mpad, int kc)
{
    const int tid  = threadIdx.x;
    const int lane = tid & 63;
    const int wid  = tid >> 6;
    const int n0 = blockIdx.x * 256 + wid * 64;
    const int m0 = blockIdx.y * 64;
    const int kbase = blockIdx.z * kc;
    const int lm = lane & 15;
    const int lk = (lane >> 4) * 8;

    unsigned aoff[4], boff[4];
    #pragma unroll
    for (int i = 0; i < 4; ++i) {
        aoff[i] = (unsigned)(m0 + i * 16 + lm) * astride + kbase + lk;
        boff[i] = (unsigned)(n0 + i * 16 + lm) * bstride + kbase + lk;
    }

    floatx4 acc[4][4];
    #pragma unroll
    for (int ms = 0; ms < 4; ++ms)
        #pragma unroll
        for (int ns = 0; ns < 4; ++ns)
            acc[ms][ns] = (floatx4){0.f, 0.f, 0.f, 0.f};

    short8 a0h[4], a0l[4], b0h[4], b0l[4];
    short8 a1h[4], a1l[4], b1h[4], b1l[4];

    const int S = kc >> 5;
    load_set(Ah, Al, Bh, Bl, aoff, boff, 0, a0h, a0l, b0h, b0l);
    for (int s = 0; s + 1 < S; s += 2) {
        load_set(Ah, Al, Bh, Bl, aoff, boff, (s + 1) << 5, a1h, a1l, b1h, b1l);
        mfma_set(a0h, a0l, b0h, b0l, acc);
        if (s + 2 < S)
            load_set(Ah, Al, Bh, Bl, aoff, boff, (s + 2) << 5, a0h, a0l, b0h, b0l);
        mfma_set(a1h, a1l, b1h, b1l, acc);
    }

    float* Cp = Cpart + (size_t)blockIdx.z * Mpad * N;
    const int lr = (lane >> 4) * 4;
    #pragma unroll
    for (int ms = 0; ms < 4; ++ms)
        #pragma unroll
        for (int ns = 0; ns < 4; ++ns)
            #pragma unroll
            for (int r = 0; r < 4; ++r)
                Cp[(size_t)(m0 + ms * 16 + lr + r) * N + n0 + ns * 16 + lm] = acc[ms][ns][r];
}

// ---------------- small kernels ----------------
__global__ __launch_bounds__(256)
void split_h_kernel(const float* __restrict__ h, unsigned short* __restrict__ Hh,
                    unsigned short* __restrict__ Hl) {
    const int idx = blockIdx.x * 256 + threadIdx.x;
    unsigned short a, b;
    split2(h[idx], a, b);
    Hh[idx] = a;
    Hl[idx] = b;
}

__global__ __launch_bounds__(256)
void build_y1_kernel(const float* __restrict__ Pp, const float* __restrict__ Qp,
                     const float* __restrict__ b1,
                     unsigned short* __restrict__ Y1h, unsigned short* __restrict__ Y1l) {
    const int r = blockIdx.x;
    const int g = r / 240;
    const int rem = r % 240;
    const int o = rem / 120;
    const int p = rem % 120;
    int i = 0, pp = p, cnt = 15;
    while (pp >= cnt) { pp -= cnt; cnt--; i++; }
    const int j = i + 1 + pp;
    const int ai = g * 16 + (o ? j : i);
    const int bi = g * 16 + (o ? i : j);
    const size_t chunk4 = (size_t)64 * 4096 / 4;
    const float4* Pr0 = (const float4*)(Pp + (size_t)ai * 4096);
    const float4* Qr0 = (const float4*)(Qp + (size_t)bi * 4096);
    const float4* Br  = (const float4*)b1;
    for (int c = threadIdx.x; c < 1024; c += 256) {
        float4 p0 = Pr0[c], p1 = Pr0[c + chunk4];
        float4 q0 = Qr0[c], q1 = Qr0[c + chunk4];
        float4 bv = Br[c];
        float s0 = silu_f(p0.x + p1.x + q0.x + q1.x + bv.x);
        float s1 = silu_f(p0.y + p1.y + q0.y + q1.y + bv.y);
        float s2 = silu_f(p0.z + p1.z + q0.z + q1.z + bv.z);
        float s3 = silu_f(p0.w + p1.w + q0.w + q1.w + bv.w);
        ushort4 hv, lv;
        split2(s0, hv.x, lv.x);
        split2(s1, hv.y, lv.y);
        split2(s2, hv.z, lv.z);
        split2(s3, hv.w, lv.w);
        *(ushort4*)&Y1h[(size_t)r * 4096 + c * 4] = hv;
        *(ushort4*)&Y1l[(size_t)r * 4096 + c * 4] = lv;
    }
}

__global__ __launch_bounds__(256)
void reduce4_silu_split(const float* __restrict__ Part, const float* __restrict__ bias,
                        unsigned short* __restrict__ Yh, unsigned short* __restrict__ Yl) {
    const size_t idx = (size_t)blockIdx.x * 256 + threadIdx.x;
    const size_t stride4 = (size_t)512 * 4096 / 4;
    const float4* p = (const float4*)Part;
    float4 v0 = p[idx], v1 = p[idx + stride4], v2 = p[idx + 2 * stride4], v3 = p[idx + 3 * stride4];
    const int col = (int)((idx * 4) & 4095);
    float4 b = *(const float4*)&bias[col];
    float s0 = silu_f(v0.x + v1.x + v2.x + v3.x + b.x);
    float s1 = silu_f(v0.y + v1.y + v2.y + v3.y + b.y);
    float s2 = silu_f(v0.z + v1.z + v2.z + v3.z + b.z);
    float s3 = silu_f(v0.w + v1.w + v2.w + v3.w + b.w);
    ushort4 hv, lv;
    split2(s0, hv.x, lv.x);
    split2(s1, hv.y, lv.y);
    split2(s2, hv.z, lv.z);
    split2(s3, hv.w, lv.w);
    *(ushort4*)&Yh[idx * 4] = hv;
    *(ushort4*)&Yl[idx * 4] = lv;
}

__global__ __launch_bounds__(256)
void reduce8_bias(const float* __restrict__ Part, const float* __restrict__ bias,
                  float* __restrict__ Hb) {
    const size_t idx = (size_t)blockIdx.x * 256 + threadIdx.x;
    const size_t stride4 = (size_t)512 * 2048 / 4;
    const float4* p = (const float4*)Part;
    float4 s = p[idx];
    #pragma unroll
    for (int c = 1; c < 8; ++c) {
        float4 v = p[idx + c * stride4];
        s.x += v.x; s.y += v.y; s.z += v.z; s.w += v.w;
    }
    const int col = (int)((idx * 4) & 2047);
    float4 b = *(const float4*)&bias[col];
    s.x += b.x; s.y += b.y; s.z += b.z; s.w += b.w;
    *(float4*)&Hb[idx * 4] = s;
}

__global__ __launch_bounds__(256)
void reduce_prod_kernel(const float* __restrict__ H, float* __restrict__ a_buf) {
    const int g = blockIdx.y;
    const int c = blockIdx.x * 256 + threadIdx.x;
    const float* base = H + (size_t)g * 240 * 2048 + c;
    float prod = 1.0f;
    for (int p = 0; p < 120; ++p) {
        float f = base[(size_t)p * 2048] - base[(size_t)(120 + p) * 2048];
        prod *= f;
    }
    a_buf[g * 2048 + c] = prod;
}

__global__ __launch_bounds__(256)
void init_tpre_kernel(const float* __restrict__ b2_0, float* __restrict__ t_pre) {
    const int idx = blockIdx.x * 256 + threadIdx.x;
    t_pre[idx] = b2_0[idx & 2047];
}

__global__ __launch_bounds__(256)
void mlp2_acc2_kernel(const float* __restrict__ a_buf, const float* __restrict__ W,
                      float* __restrict__ t_pre) {
    __shared__ float a0s[256], a1s[256];
    const int kc = blockIdx.y, nc = blockIdx.x, t = threadIdx.x;
    a0s[t] = a_buf[kc * 256 + t];
    a1s[t] = a_buf[2048 + kc * 256 + t];
    __syncthreads();
    const int n = nc * 256 + t;
    const float* Wp = W + (size_t)(kc * 256) * 2048 + n;
    float s0 = 0.f, s1 = 0.f;
    #pragma unroll 8
    for (int kk = 0; kk < 256; ++kk) {
        float w = Wp[(size_t)kk * 2048];
        s0 = fmaf(a0s[kk], w, s0);
        s1 = fmaf(a1s[kk], w, s1);
    }
    atomicAdd(&t_pre[n], s0);
    atomicAdd(&t_pre[2048 + n], s1);
}

__global__ __launch_bounds__(256)
void finalize_kernel(const float* __restrict__ t_pre, const float* __restrict__ w2_1,
                     const float* __restrict__ b2_1, float* __restrict__ out) {
    __shared__ float red[256];
    const int tid = threadIdx.x;
    float result = 0.0f;
    for (int g = 0; g < 2; ++g) {
        float s = 0.f;
        for (int n = tid; n < 2048; n += 256)
            s += tanhf(t_pre[g * 2048 + n]) * w2_1[n];
        red[tid] = s;
        __syncthreads();
        for (int off = 128; off > 0; off >>= 1) {
            if (tid < off) red[tid] += red[tid + off];
            __syncthreads();
        }
        if (tid == 0) result += logf(fabsf(red[0] + b2_1[0]));
        __syncthreads();
    }
    if (tid == 0) out[0] = result;
}

extern "C" void kernel_launch(void* const* d_in, const int* in_sizes, int n_in,
                              void* d_out, int out_size, void* d_ws, size_t ws_size,
                              hipStream_t stream) {
    const float* h_one = (const float*)d_in[0];
    const float* w1_0  = (const float*)d_in[1];
    const float* b1_0  = (const float*)d_in[2];
    const float* w1_1  = (const float*)d_in[3];
    const float* b1_1  = (const float*)d_in[4];
    const float* w1_2  = (const float*)d_in[5];
    const float* b1_2  = (const float*)d_in[6];
    const float* w2_0  = (const float*)d_in[7];
    const float* b2_0  = (const float*)d_in[8];
    const float* w2_1  = (const float*)d_in[9];
    const float* b2_1  = (const float*)d_in[10];
    float* out = (float*)d_out;

    char* ws = (char*)d_ws;
    // region0: W10t (33.5 MB), later PartL1 (4 x 512 x 4096 f32 = 33.5 MB)
    unsigned short* W10t_h = (unsigned short*)ws;
    unsigned short* W10t_l = W10t_h + (size_t)4096 * 2048;
    float*          PartL1 = (float*)ws;
    ws += (size_t)4096 * 2048 * 2 * 2;
    // region1: W11t (67 MB), later PartL2 (8 x 512 x 2048 f32 = 33.5 MB)
    unsigned short* W11t_h = (unsigned short*)ws;
    unsigned short* W11t_l = W11t_h + (size_t)4096 * 4096;
    float*          PartL2 = (float*)ws;
    ws += (size_t)4096 * 4096 * 2 * 2;
    // region2: W12t (33.5 MB), live through L2
    unsigned short* W12t_h = (unsigned short*)ws;
    unsigned short* W12t_l = W12t_h + (size_t)2048 * 4096;
    ws += (size_t)2048 * 4096 * 2 * 2;
    unsigned short* Hh  = (unsigned short*)ws;  ws += (size_t)64 * 1024 * 2;
    unsigned short* Hl  = (unsigned short*)ws;  ws += (size_t)64 * 1024 * 2;
    float* Pp  = (float*)ws;                    ws += (size_t)2 * 64 * 4096 * 4;
    float* Qp  = (float*)ws;                    ws += (size_t)2 * 64 * 4096 * 4;
    unsigned short* Y1h = (unsigned short*)ws;  ws += (size_t)512 * 4096 * 2;
    unsigned short* Y1l = (unsigned short*)ws;  ws += (size_t)512 * 4096 * 2;
    unsigned short* Y2h = (unsigned short*)ws;  ws += (size_t)512 * 4096 * 2;
    unsigned short* Y2l = (unsigned short*)ws;  ws += (size_t)512 * 4096 * 2;
    float* Hb    = (float*)ws;                  ws += (size_t)512 * 2048 * 4;
    float* a_buf = (float*)ws;                  ws += (size_t)2 * 2048 * 4;
    float* t_pre = (float*)ws;                  ws += (size_t)2 * 2048 * 4;

    // --- all weight transposes up front (one kernel) ---
    transpose_split_all<<<32768, 256, 0, stream>>>(w1_0, w1_1, w1_2,
                                                   W10t_h, W10t_l, W11t_h, W11t_l, W12t_h, W12t_l);
    split_h_kernel<<<128, 256, 0, stream>>>(h_one, Hh, Hl);

    // P/Q (M=64 incl. pad): LDS-free kernel
    mfma_gemm_df<<<dim3(16, 1, 2), 256, 0, stream>>>(Hh, Hl, 1024, W10t_h, W10t_l, 2048,
                                                     Pp, 4096, 64, 512);
    mfma_gemm_df<<<dim3(16, 1, 2), 256, 0, stream>>>(Hh, Hl, 1024, W10t_h + 1024, W10t_l + 1024, 2048,
                                                     Qp, 4096, 64, 512);
    build_y1_kernel<<<480, 256, 0, stream>>>(Pp, Qp, b1_0, Y1h, Y1l);

    // L1: Y2 = silu(Y1 @ W1_1 + b1_1)  M=512 N=4096 K=4096, Z=4
    gemm128<<<dim3(32, 4, 4), 256, 0, stream>>>(Y1h, Y1l, W11t_h, W11t_l, 4096,
                                                PartL1, 4096, 512, 1024);
    reduce4_silu_split<<<2048, 256, 0, stream>>>(PartL1, b1_1, Y2h, Y2l);

    // L2: Hb = Y2 @ W1_2 + b1_2  M=512 N=2048 K=4096, Z=8
    gemm128<<<dim3(16, 4, 8), 256, 0, stream>>>(Y2h, Y2l, W12t_h, W12t_l, 4096,
                                                PartL2, 2048, 512, 512);
    reduce8_bias<<<1024, 256, 0, stream>>>(PartL2, b1_2, Hb);

    // --- tail ---
    reduce_prod_kernel<<<dim3(8, 2), 256, 0, stream>>>(Hb, a_buf);
    init_tpre_kernel<<<16, 256, 0, stream>>>(b2_0, t_pre);
    mlp2_acc2_kernel<<<dim3(8, 8), 256, 0, stream>>>(a_buf, w2_0, t_pre);
    finalize_kernel<<<1, 256, 0, stream>>>(t_pre, w2_1, b2_1, out);
}

// Round 5
// 380.861 us; speedup vs baseline: 2.3508x; 1.0939x over previous
//
#include <hip/hip_runtime.h>
#include <hip/hip_bf16.h>
#include <math.h>

// ---------------------------------------------------------------------------
// Round 5: fast 64x64-tile weight transpose+split; fewer launches.
//   - transpose_split_all: 64x64 tiles, float4 loads -> LDS [64][65] (2-way
//     broadcast banks on read = free) -> short8 (16B) k-contiguous stores.
//     split_h folded in as tail blocks.
//   - pq_gemm: both P and Q halves in one launch (grid z = 4).
//   - mlp2 writes per-kc partials (no atomics); finalize sums them.
//   - gemm128 (m97-style LDS-staged split-bf16 MFMA) unchanged from round 4.
// ---------------------------------------------------------------------------

typedef __attribute__((ext_vector_type(8))) short short8;
typedef __attribute__((ext_vector_type(4))) float floatx4;

#define AS1 __attribute__((address_space(1)))
#define AS3 __attribute__((address_space(3)))
#define GLD16(g, l) __builtin_amdgcn_global_load_lds((AS1 const unsigned int*)(g), (AS3 unsigned int*)(l), 16, 0, 0)

__device__ __forceinline__ float silu_f(float x) {
    return x / (1.0f + __expf(-x));
}

// RNE split of fp32 into two bf16 (hi + lo)
__device__ __forceinline__ void split2(float x, unsigned short& hi, unsigned short& lo) {
    unsigned u = __float_as_uint(x);
    unsigned r = u + 0x7FFFu + ((u >> 16) & 1u);
    unsigned short h = (unsigned short)(r >> 16);
    float hf = __uint_as_float((unsigned)h << 16);
    float rem = x - hf;
    unsigned u2 = __float_as_uint(rem);
    unsigned r2 = u2 + 0x7FFFu + ((u2 >> 16) & 1u);
    hi = h;
    lo = (unsigned short)(r2 >> 16);
}

// ---------------- transpose + split, 64x64 tiles + split_h tail ------------
// W[K][N] f32 -> Th[N][K], Tl[N][K] bf16 (k-contiguous)
__global__ __launch_bounds__(256)
void transpose_split_all(const float* __restrict__ w10, const float* __restrict__ w11,
                         const float* __restrict__ w12, const float* __restrict__ h_one,
                         unsigned short* __restrict__ t10h, unsigned short* __restrict__ t10l,
                         unsigned short* __restrict__ t11h, unsigned short* __restrict__ t11l,
                         unsigned short* __restrict__ t12h, unsigned short* __restrict__ t12l,
                         unsigned short* __restrict__ Hh, unsigned short* __restrict__ Hl) {
    const int t = threadIdx.x;
    int id = blockIdx.x;

    if (id >= 8192) {
        // split_h tail: 8 blocks x 4096 elements (h_one = 32x1024)
        const int base = (id - 8192) * 4096 + t * 16;
        #pragma unroll
        for (int j = 0; j < 4; ++j) {
            float4 v = *(const float4*)&h_one[base + 4 * j];
            ushort4 hv, lv;
            split2(v.x, hv.x, lv.x);
            split2(v.y, hv.y, lv.y);
            split2(v.z, hv.z, lv.z);
            split2(v.w, hv.w, lv.w);
            *(ushort4*)&Hh[base + 4 * j] = hv;
            *(ushort4*)&Hl[base + 4 * j] = lv;
        }
        return;
    }

    const float* W;
    unsigned short *Th, *Tl;
    int K, N, nt, kt;
    if (id < 2048)       { W = w10; Th = t10h; Tl = t10l; K = 2048; N = 4096; nt = id & 63; kt = id >> 6; }
    else if (id < 6144)  { id -= 2048; W = w11; Th = t11h; Tl = t11l; K = 4096; N = 4096; nt = id & 63; kt = id >> 6; }
    else                 { id -= 6144; W = w12; Th = t12h; Tl = t12l; K = 4096; N = 2048; nt = id & 31; kt = id >> 5; }

    __shared__ float tile[64][65];
    const int n0 = nt * 64;
    const int k0 = kt * 64;

    // load: 64 rows (k) x 64 cols (n); thread: row = t>>2, 16 cols from (t&3)*16
    const int lr = t >> 2;
    const int lc = (t & 3) * 16;
    const float* src = &W[(size_t)(k0 + lr) * N + n0 + lc];
    #pragma unroll
    for (int j = 0; j < 4; ++j) {
        float4 v = *(const float4*)(src + 4 * j);
        tile[lr][lc + 4 * j + 0] = v.x;
        tile[lr][lc + 4 * j + 1] = v.y;
        tile[lr][lc + 4 * j + 2] = v.z;
        tile[lr][lc + 4 * j + 3] = v.w;
    }
    __syncthreads();

    // store: thread: n = t>>2, k range (t&3)*16 .. +15
    const int sn   = t >> 2;
    const int koff = (t & 3) * 16;
    unsigned short hv[16], lv[16];
    #pragma unroll
    for (int kk = 0; kk < 16; ++kk)
        split2(tile[koff + kk][sn], hv[kk], lv[kk]);
    unsigned short* dh = &Th[(size_t)(n0 + sn) * K + k0 + koff];
    unsigned short* dl = &Tl[(size_t)(n0 + sn) * K + k0 + koff];
    *(short8*)(dh)     = *(short8*)&hv[0];
    *(short8*)(dh + 8) = *(short8*)&hv[8];
    *(short8*)(dl)     = *(short8*)&lv[0];
    *(short8*)(dl + 8) = *(short8*)&lv[8];
}

// ---------------- m97-style LDS-staged GEMM, 128x128 tile ------------------
__global__ __launch_bounds__(256, 2)
void gemm128(const unsigned short* __restrict__ Ah, const unsigned short* __restrict__ Al,
             const unsigned short* __restrict__ Bh, const unsigned short* __restrict__ Bl,
             int K, float* __restrict__ Cpart, int N, int Mtot, int kc)
{
    __shared__ __align__(16) unsigned short As[2][128][32];
    __shared__ __align__(16) unsigned short Bs[2][128][32];

    const int tid  = threadIdx.x;
    const int lane = tid & 63;
    const int wid  = tid >> 6;
    const int n0 = blockIdx.x * 128;
    const int m0 = blockIdx.y * 128;
    const int kbase = blockIdx.z * kc;

    const int srow   = wid * 32 + (lane >> 2);
    const int schunk = (lane & 3) ^ ((srow >> 1) & 3);
    const unsigned short* gA0h = Ah + (size_t)(m0 + srow) * K + kbase + schunk * 8;
    const unsigned short* gA1h = gA0h + (size_t)16 * K;
    const unsigned short* gA0l = Al + (size_t)(m0 + srow) * K + kbase + schunk * 8;
    const unsigned short* gA1l = gA0l + (size_t)16 * K;
    const unsigned short* gB0h = Bh + (size_t)(n0 + srow) * K + kbase + schunk * 8;
    const unsigned short* gB1h = gB0h + (size_t)16 * K;
    const unsigned short* gB0l = Bl + (size_t)(n0 + srow) * K + kbase + schunk * 8;
    const unsigned short* gB1l = gB0l + (size_t)16 * K;
    unsigned short* lA0h = &As[0][wid * 32][0];
    unsigned short* lA1h = &As[0][wid * 32 + 16][0];
    unsigned short* lA0l = &As[1][wid * 32][0];
    unsigned short* lA1l = &As[1][wid * 32 + 16][0];
    unsigned short* lB0h = &Bs[0][wid * 32][0];
    unsigned short* lB1h = &Bs[0][wid * 32 + 16][0];
    unsigned short* lB0l = &Bs[1][wid * 32][0];
    unsigned short* lB1l = &Bs[1][wid * 32 + 16][0];

    const int mhalf = wid >> 1;
    const int nhalf = wid & 1;
    const int lm = lane & 15;
    const int q  = lane >> 4;
    int aoffs[4], boffs[4];
    #pragma unroll
    for (int f = 0; f < 4; ++f) {
        int arow = mhalf * 64 + f * 16 + lm;
        int aslot = q ^ ((arow >> 1) & 3);
        aoffs[f] = arow * 32 + aslot * 8;
        int brow = nhalf * 64 + f * 16 + lm;
        int bslot = q ^ ((brow >> 1) & 3);
        boffs[f] = brow * 32 + bslot * 8;
    }
    const unsigned short* AsF = &As[0][0][0];
    const unsigned short* BsF = &Bs[0][0][0];

    floatx4 acc[4][4];
    #pragma unroll
    for (int ms = 0; ms < 4; ++ms)
        #pragma unroll
        for (int ns = 0; ns < 4; ++ns)
            acc[ms][ns] = (floatx4){0.f, 0.f, 0.f, 0.f};

    const int S = kc >> 5;
    for (int s = 0; s < S; ++s) {
        const int ko = s << 5;
        __syncthreads();
        GLD16(gA0h + ko, lA0h);
        GLD16(gA1h + ko, lA1h);
        GLD16(gA0l + ko, lA0l);
        GLD16(gA1l + ko, lA1l);
        GLD16(gB0h + ko, lB0h);
        GLD16(gB1h + ko, lB1h);
        GLD16(gB0l + ko, lB0l);
        GLD16(gB1l + ko, lB1l);
        __syncthreads();

        short8 afh[4], afl[4], bfh[4], bfl[4];
        #pragma unroll
        for (int f = 0; f < 4; ++f) {
            afh[f] = *(const short8*)(AsF + aoffs[f]);
            afl[f] = *(const short8*)(AsF + 4096 + aoffs[f]);
            bfh[f] = *(const short8*)(BsF + boffs[f]);
            bfl[f] = *(const short8*)(BsF + 4096 + boffs[f]);
        }
        #pragma unroll
        for (int ms = 0; ms < 4; ++ms)
            #pragma unroll
            for (int ns = 0; ns < 4; ++ns)
                acc[ms][ns] = __builtin_amdgcn_mfma_f32_16x16x32_bf16(afh[ms], bfh[ns], acc[ms][ns], 0, 0, 0);
        #pragma unroll
        for (int ms = 0; ms < 4; ++ms)
            #pragma unroll
            for (int ns = 0; ns < 4; ++ns)
                acc[ms][ns] = __builtin_amdgcn_mfma_f32_16x16x32_bf16(afl[ms], bfh[ns], acc[ms][ns], 0, 0, 0);
        #pragma unroll
        for (int ms = 0; ms < 4; ++ms)
            #pragma unroll
            for (int ns = 0; ns < 4; ++ns)
                acc[ms][ns] = __builtin_amdgcn_mfma_f32_16x16x32_bf16(afh[ms], bfl[ns], acc[ms][ns], 0, 0, 0);
    }

    float* Cp = Cpart + (size_t)blockIdx.z * Mtot * N;
    const int lr = (lane >> 4) * 4;
    #pragma unroll
    for (int ms = 0; ms < 4; ++ms)
        #pragma unroll
        for (int ns = 0; ns < 4; ++ns)
            #pragma unroll
            for (int r = 0; r < 4; ++r)
                Cp[(size_t)(m0 + mhalf * 64 + ms * 16 + lr + r) * N + n0 + nhalf * 64 + ns * 16 + lm] = acc[ms][ns][r];
}

// ---------------- P/Q GEMM (LDS-free, both halves in one launch) -----------
__device__ __forceinline__ void load_set(
    const unsigned short* __restrict__ Ah, const unsigned short* __restrict__ Al,
    const unsigned short* __restrict__ Bh, const unsigned short* __restrict__ Bl,
    const unsigned aoff[4], const unsigned boff[4], int koff,
    short8 (&ah)[4], short8 (&al)[4], short8 (&bh)[4], short8 (&bl)[4])
{
    #pragma unroll
    for (int i = 0; i < 4; ++i) {
        ah[i] = *(const short8*)(Ah + aoff[i] + koff);
        al[i] = *(const short8*)(Al + aoff[i] + koff);
        bh[i] = *(const short8*)(Bh + boff[i] + koff);
        bl[i] = *(const short8*)(Bl + boff[i] + koff);
    }
}

__device__ __forceinline__ void mfma_set(
    const short8 (&ah)[4], const short8 (&al)[4],
    const short8 (&bh)[4], const short8 (&bl)[4],
    floatx4 (&acc)[4][4])
{
    #pragma unroll
    for (int ms = 0; ms < 4; ++ms)
        #pragma unroll
        for (int ns = 0; ns < 4; ++ns)
            acc[ms][ns] = __builtin_amdgcn_mfma_f32_16x16x32_bf16(ah[ms], bh[ns], acc[ms][ns], 0, 0, 0);
    #pragma unroll
    for (int ms = 0; ms < 4; ++ms)
        #pragma unroll
        for (int ns = 0; ns < 4; ++ns)
            acc[ms][ns] = __builtin_amdgcn_mfma_f32_16x16x32_bf16(al[ms], bh[ns], acc[ms][ns], 0, 0, 0);
    #pragma unroll
    for (int ms = 0; ms < 4; ++ms)
        #pragma unroll
        for (int ns = 0; ns < 4; ++ns)
            acc[ms][ns] = __builtin_amdgcn_mfma_f32_16x16x32_bf16(ah[ms], bl[ns], acc[ms][ns], 0, 0, 0);
}

// grid (16,1,4): z&1 = k-chunk (512 each), z>>1 = P(0)/Q(1).
// A = Hh/Hl [64][1024]; B = W10t [4096][2048]; out PQ[z][64][4096].
__global__ __launch_bounds__(256, 2)
void pq_gemm(const unsigned short* __restrict__ Ah, const unsigned short* __restrict__ Al,
             const unsigned short* __restrict__ Bh0, const unsigned short* __restrict__ Bl0,
             float* __restrict__ PQ)
{
    const int tid  = threadIdx.x;
    const int lane = tid & 63;
    const int wid  = tid >> 6;
    const int n0 = blockIdx.x * 256 + wid * 64;
    const int z  = blockIdx.z;
    const int kbase = (z & 1) * 512;
    const unsigned short* Bh = Bh0 + (z >> 1) * 1024;
    const unsigned short* Bl = Bl0 + (z >> 1) * 1024;
    const int lm = lane & 15;
    const int lk = (lane >> 4) * 8;

    unsigned aoff[4], boff[4];
    #pragma unroll
    for (int i = 0; i < 4; ++i) {
        aoff[i] = (unsigned)(i * 16 + lm) * 1024 + kbase + lk;
        boff[i] = (unsigned)(n0 + i * 16 + lm) * 2048 + kbase + lk;
    }

    floatx4 acc[4][4];
    #pragma unroll
    for (int ms = 0; ms < 4; ++ms)
        #pragma unroll
        for (int ns = 0; ns < 4; ++ns)
            acc[ms][ns] = (floatx4){0.f, 0.f, 0.f, 0.f};

    short8 a0h[4], a0l[4], b0h[4], b0l[4];
    short8 a1h[4], a1l[4], b1h[4], b1l[4];

    load_set(Ah, Al, Bh, Bl, aoff, boff, 0, a0h, a0l, b0h, b0l);
    for (int s = 0; s + 1 < 16; s += 2) {
        load_set(Ah, Al, Bh, Bl, aoff, boff, (s + 1) << 5, a1h, a1l, b1h, b1l);
        mfma_set(a0h, a0l, b0h, b0l, acc);
        if (s + 2 < 16)
            load_set(Ah, Al, Bh, Bl, aoff, boff, (s + 2) << 5, a0h, a0l, b0h, b0l);
        mfma_set(a1h, a1l, b1h, b1l, acc);
    }

    float* Cp = PQ + (size_t)z * 64 * 4096;
    const int lr = (lane >> 4) * 4;
    #pragma unroll
    for (int ms = 0; ms < 4; ++ms)
        #pragma unroll
        for (int ns = 0; ns < 4; ++ns)
            #pragma unroll
            for (int r = 0; r < 4; ++r)
                Cp[(size_t)(ms * 16 + lr + r) * 4096 + n0 + ns * 16 + lm] = acc[ms][ns][r];
}

// ---------------- small kernels ----------------
// PQ layout: z=0,1 P chunks; z=2,3 Q chunks.
__global__ __launch_bounds__(256)
void build_y1_kernel(const float* __restrict__ PQ, const float* __restrict__ b1,
                     unsigned short* __restrict__ Y1h, unsigned short* __restrict__ Y1l) {
    const int r = blockIdx.x;
    const int g = r / 240;
    const int rem = r % 240;
    const int o = rem / 120;
    const int p = rem % 120;
    int i = 0, pp = p, cnt = 15;
    while (pp >= cnt) { pp -= cnt; cnt--; i++; }
    const int j = i + 1 + pp;
    const int ai = g * 16 + (o ? j : i);
    const int bi = g * 16 + (o ? i : j);
    const size_t chunk4 = (size_t)64 * 4096 / 4;
    const float4* Pr0 = (const float4*)(PQ + (size_t)ai * 4096);
    const float4* Qr0 = (const float4*)(PQ + (size_t)2 * 64 * 4096 + (size_t)bi * 4096);
    const float4* Br  = (const float4*)b1;
    for (int c = threadIdx.x; c < 1024; c += 256) {
        float4 p0 = Pr0[c], p1 = Pr0[c + chunk4];
        float4 q0 = Qr0[c], q1 = Qr0[c + chunk4];
        float4 bv = Br[c];
        float s0 = silu_f(p0.x + p1.x + q0.x + q1.x + bv.x);
        float s1 = silu_f(p0.y + p1.y + q0.y + q1.y + bv.y);
        float s2 = silu_f(p0.z + p1.z + q0.z + q1.z + bv.z);
        float s3 = silu_f(p0.w + p1.w + q0.w + q1.w + bv.w);
        ushort4 hv, lv;
        split2(s0, hv.x, lv.x);
        split2(s1, hv.y, lv.y);
        split2(s2, hv.z, lv.z);
        split2(s3, hv.w, lv.w);
        *(ushort4*)&Y1h[(size_t)r * 4096 + c * 4] = hv;
        *(ushort4*)&Y1l[(size_t)r * 4096 + c * 4] = lv;
    }
}

__global__ __launch_bounds__(256)
void reduce4_silu_split(const float* __restrict__ Part, const float* __restrict__ bias,
                        unsigned short* __restrict__ Yh, unsigned short* __restrict__ Yl) {
    const size_t idx = (size_t)blockIdx.x * 256 + threadIdx.x;
    const size_t stride4 = (size_t)512 * 4096 / 4;
    const float4* p = (const float4*)Part;
    float4 v0 = p[idx], v1 = p[idx + stride4], v2 = p[idx + 2 * stride4], v3 = p[idx + 3 * stride4];
    const int col = (int)((idx * 4) & 4095);
    float4 b = *(const float4*)&bias[col];
    float s0 = silu_f(v0.x + v1.x + v2.x + v3.x + b.x);
    float s1 = silu_f(v0.y + v1.y + v2.y + v3.y + b.y);
    float s2 = silu_f(v0.z + v1.z + v2.z + v3.z + b.z);
    float s3 = silu_f(v0.w + v1.w + v2.w + v3.w + b.w);
    ushort4 hv, lv;
    split2(s0, hv.x, lv.x);
    split2(s1, hv.y, lv.y);
    split2(s2, hv.z, lv.z);
    split2(s3, hv.w, lv.w);
    *(ushort4*)&Yh[idx * 4] = hv;
    *(ushort4*)&Yl[idx * 4] = lv;
}

__global__ __launch_bounds__(256)
void reduce8_bias(const float* __restrict__ Part, const float* __restrict__ bias,
                  float* __restrict__ Hb) {
    const size_t idx = (size_t)blockIdx.x * 256 + threadIdx.x;
    const size_t stride4 = (size_t)512 * 2048 / 4;
    const float4* p = (const float4*)Part;
    float4 s = p[idx];
    #pragma unroll
    for (int c = 1; c < 8; ++c) {
        float4 v = p[idx + c * stride4];
        s.x += v.x; s.y += v.y; s.z += v.z; s.w += v.w;
    }
    const int col = (int)((idx * 4) & 2047);
    float4 b = *(const float4*)&bias[col];
    s.x += b.x; s.y += b.y; s.z += b.z; s.w += b.w;
    *(float4*)&Hb[idx * 4] = s;
}

__global__ __launch_bounds__(256)
void reduce_prod_kernel(const float* __restrict__ H, float* __restrict__ a_buf) {
    const int g = blockIdx.y;
    const int c = blockIdx.x * 256 + threadIdx.x;
    const float* base = H + (size_t)g * 240 * 2048 + c;
    float prod = 1.0f;
    for (int p = 0; p < 120; ++p) {
        float f = base[(size_t)p * 2048] - base[(size_t)(120 + p) * 2048];
        prod *= f;
    }
    a_buf[g * 2048 + c] = prod;
}

// Part2[kc][g][n] = sum_{k in chunk kc} a[g][k] * W2_0[k][n]  (no atomics)
__global__ __launch_bounds__(256)
void mlp2_acc2_kernel(const float* __restrict__ a_buf, const float* __restrict__ W,
                      float* __restrict__ Part2) {
    __shared__ float a0s[256], a1s[256];
    const int kc = blockIdx.y, nc = blockIdx.x, t = threadIdx.x;
    a0s[t] = a_buf[kc * 256 + t];
    a1s[t] = a_buf[2048 + kc * 256 + t];
    __syncthreads();
    const int n = nc * 256 + t;
    const float* Wp = W + (size_t)(kc * 256) * 2048 + n;
    float s0 = 0.f, s1 = 0.f;
    #pragma unroll 8
    for (int kk = 0; kk < 256; ++kk) {
        float w = Wp[(size_t)kk * 2048];
        s0 = fmaf(a0s[kk], w, s0);
        s1 = fmaf(a1s[kk], w, s1);
    }
    Part2[kc * 4096 + n] = s0;
    Part2[kc * 4096 + 2048 + n] = s1;
}

__global__ __launch_bounds__(256)
void finalize_kernel(const float* __restrict__ Part2, const float* __restrict__ b2_0,
                     const float* __restrict__ w2_1, const float* __restrict__ b2_1,
                     float* __restrict__ out) {
    __shared__ float red[256];
    const int tid = threadIdx.x;
    float result = 0.0f;
    for (int g = 0; g < 2; ++g) {
        float s = 0.f;
        for (int n = tid; n < 2048; n += 256) {
            float acc = b2_0[n];
            #pragma unroll
            for (int kc = 0; kc < 8; ++kc)
                acc += Part2[kc * 4096 + g * 2048 + n];
            s += tanhf(acc) * w2_1[n];
        }
        red[tid] = s;
        __syncthreads();
        for (int off = 128; off > 0; off >>= 1) {
            if (tid < off) red[tid] += red[tid + off];
            __syncthreads();
        }
        if (tid == 0) result += logf(fabsf(red[0] + b2_1[0]));
        __syncthreads();
    }
    if (tid == 0) out[0] = result;
}

extern "C" void kernel_launch(void* const* d_in, const int* in_sizes, int n_in,
                              void* d_out, int out_size, void* d_ws, size_t ws_size,
                              hipStream_t stream) {
    const float* h_one = (const float*)d_in[0];
    const float* w1_0  = (const float*)d_in[1];
    const float* b1_0  = (const float*)d_in[2];
    const float* w1_1  = (const float*)d_in[3];
    const float* b1_1  = (const float*)d_in[4];
    const float* w1_2  = (const float*)d_in[5];
    const float* b1_2  = (const float*)d_in[6];
    const float* w2_0  = (const float*)d_in[7];
    const float* b2_0  = (const float*)d_in[8];
    const float* w2_1  = (const float*)d_in[9];
    const float* b2_1  = (const float*)d_in[10];
    float* out = (float*)d_out;

    char* ws = (char*)d_ws;
    // region0: W10t (33.5 MB), later PartL1 (4 x 512 x 4096 f32)
    unsigned short* W10t_h = (unsigned short*)ws;
    unsigned short* W10t_l = W10t_h + (size_t)4096 * 2048;
    float*          PartL1 = (float*)ws;
    ws += (size_t)4096 * 2048 * 2 * 2;
    // region1: W11t (67 MB), later PartL2 (8 x 512 x 2048 f32)
    unsigned short* W11t_h = (unsigned short*)ws;
    unsigned short* W11t_l = W11t_h + (size_t)4096 * 4096;
    float*          PartL2 = (float*)ws;
    ws += (size_t)4096 * 4096 * 2 * 2;
    // region2: W12t (33.5 MB), live through L2
    unsigned short* W12t_h = (unsigned short*)ws;
    unsigned short* W12t_l = W12t_h + (size_t)2048 * 4096;
    ws += (size_t)2048 * 4096 * 2 * 2;
    unsigned short* Hh  = (unsigned short*)ws;  ws += (size_t)64 * 1024 * 2;
    unsigned short* Hl  = (unsigned short*)ws;  ws += (size_t)64 * 1024 * 2;
    float* PQ  = (float*)ws;                    ws += (size_t)4 * 64 * 4096 * 4;
    unsigned short* Y1h = (unsigned short*)ws;  ws += (size_t)512 * 4096 * 2;
    unsigned short* Y1l = (unsigned short*)ws;  ws += (size_t)512 * 4096 * 2;
    unsigned short* Y2h = (unsigned short*)ws;  ws += (size_t)512 * 4096 * 2;
    unsigned short* Y2l = (unsigned short*)ws;  ws += (size_t)512 * 4096 * 2;
    float* Hb    = (float*)ws;                  ws += (size_t)512 * 2048 * 4;
    float* a_buf = (float*)ws;                  ws += (size_t)2 * 2048 * 4;
    float* Part2 = (float*)ws;                  ws += (size_t)8 * 2 * 2048 * 4;

    // weight transposes + h split (one kernel, 8200 blocks)
    transpose_split_all<<<8200, 256, 0, stream>>>(w1_0, w1_1, w1_2, h_one,
                                                  W10t_h, W10t_l, W11t_h, W11t_l,
                                                  W12t_h, W12t_l, Hh, Hl);

    // P/Q: one launch, 4 z-slices
    pq_gemm<<<dim3(16, 1, 4), 256, 0, stream>>>(Hh, Hl, W10t_h, W10t_l, PQ);
    build_y1_kernel<<<480, 256, 0, stream>>>(PQ, b1_0, Y1h, Y1l);

    // L1: Y2 = silu(Y1 @ W1_1 + b1_1)  M=512 N=4096 K=4096, Z=4
    gemm128<<<dim3(32, 4, 4), 256, 0, stream>>>(Y1h, Y1l, W11t_h, W11t_l, 4096,
                                                PartL1, 4096, 512, 1024);
    reduce4_silu_split<<<2048, 256, 0, stream>>>(PartL1, b1_1, Y2h, Y2l);

    // L2: Hb = Y2 @ W1_2 + b1_2  M=512 N=2048 K=4096, Z=8
    gemm128<<<dim3(16, 4, 8), 256, 0, stream>>>(Y2h, Y2l, W12t_h, W12t_l, 4096,
                                                PartL2, 2048, 512, 512);
    reduce8_bias<<<1024, 256, 0, stream>>>(PartL2, b1_2, Hb);

    // tail
    reduce_prod_kernel<<<dim3(8, 2), 256, 0, stream>>>(Hb, a_buf);
    mlp2_acc2_kernel<<<dim3(8, 8), 256, 0, stream>>>(a_buf, w2_0, Part2);
    finalize_kernel<<<1, 256, 0, stream>>>(Part2, b2_0, w2_1, b2_1, out);
}